// Round 1
// baseline (18626.482 us; speedup 1.0000x reference)
//
#include <hip/hip_runtime.h>
#include <cstdint>

typedef unsigned short u16;
typedef unsigned int   u32;
typedef __bf16 v8bf __attribute__((ext_vector_type(8)));
typedef float  v4f  __attribute__((ext_vector_type(4)));

#define T_STEPS 1024
#define G3 1536

// ws layout (bytes). Total ~330.3 MB.
#define OFF_XBF   0ull          // x bf16               [65536,512]   67,108,864
#define OFF_OUTS1 67108864ull   // layer-1 outs bf16    [65536,512]   67,108,864
#define OFF_XG    134217728ull  // xg bf16              [65536,1536] 201,326,592
#define OFF_WII   335544320ull  // Wii bf16             [2,1536,512]   3,145,728
#define OFF_WPACK 338690048ull  // packed B-frag weights              7,340,032
#define OFF_BIASF 346030080ull  // folded gate bias f32 [2,1536]          12,288
#define OFF_HC    346042368ull  // h/c ping-pong bf16 [2][4][16][1024]  262,144
#define OFF_CNT   346304512ull  // 4 group counters, 256B apart           1,024

__device__ __forceinline__ u16 f2b(float f) {
  u32 u = __builtin_bit_cast(u32, f);
  u += 0x7fffu + ((u >> 16) & 1u);
  return (u16)(u >> 16);
}
__device__ __forceinline__ float b2f(u16 h) {
  u32 u = ((u32)h) << 16;
  return __builtin_bit_cast(float, u);
}
__device__ __forceinline__ float sigm(float x) { return 1.0f / (1.0f + __expf(-x)); }

// ---------------- prep kernels ----------------

__global__ void k_cvt(const float* __restrict__ s, u16* __restrict__ d, int n4) {
  int i = blockIdx.x * blockDim.x + threadIdx.x;
  int st = gridDim.x * blockDim.x;
  for (; i < n4; i += st) {
    float4 v = reinterpret_cast<const float4*>(s)[i];
    u32 lo = (u32)f2b(v.x) | ((u32)f2b(v.y) << 16);
    u32 hi = (u32)f2b(v.z) | ((u32)f2b(v.w) << 16);
    uint2 pk; pk.x = lo; pk.y = hi;
    reinterpret_cast<uint2*>(d)[i] = pk;
  }
}

__global__ void k_fold(const float* __restrict__ a, const float* __restrict__ b,
                       const float* __restrict__ c, float* __restrict__ o, int n) {
  int i = blockIdx.x * blockDim.x + threadIdx.x;
  if (i < n) o[i] = a[i] + b[i] + c[i];
}

// Pack recurrent weights into MFMA B-fragment order, bf16.
// Layout: [l][s][chunk c][lane][8 bf16] ; c<96: gate tile tau=c/32, kk=c%32 (K=1024: k<512->Wih, k>=512->Wic)
//         c>=96: cellgate (Whh), kk=c-96 (K=512)
// B-frag: lane holds B[k = kk*32 + (lane>>4)*8 + i][col = lane&15], B[k][col] = W[col][k].
__global__ void k_pack(const float* __restrict__ Wih, const float* __restrict__ Wic,
                       const float* __restrict__ Whh, u16* __restrict__ wp) {
  int t = blockIdx.x * blockDim.x + threadIdx.x;
  if (t >= 2 * 32 * 112 * 64) return;
  int lane = t & 63; int rest = t >> 6;
  int c = rest % 112; rest /= 112;
  int s = rest & 31; int l = rest >> 5;
  int col16 = lane & 15, kq = lane >> 4;
  const float* src;
  if (c < 96) {
    int tau = c >> 5, kk = c & 31;
    int col = tau * 512 + s * 16 + col16;
    int k = kk * 32 + kq * 8;
    src = (k < 512) ? (Wih + ((size_t)l * G3 + col) * 512 + k)
                    : (Wic + ((size_t)l * G3 + col) * 512 + (k - 512));
  } else {
    int kk = c - 96;
    int col = s * 16 + col16;
    int k = kk * 32 + kq * 8;
    src = Whh + ((size_t)l * 512 + col) * 512 + k;
  }
  u16 o[8];
#pragma unroll
  for (int i = 0; i < 8; ++i) o[i] = f2b(src[i]);
  uint4 v;
  v.x = (u32)o[0] | ((u32)o[1] << 16);
  v.y = (u32)o[2] | ((u32)o[3] << 16);
  v.z = (u32)o[4] | ((u32)o[5] << 16);
  v.w = (u32)o[6] | ((u32)o[7] << 16);
  reinterpret_cast<uint4*>(wp)[t] = v;
}

// ---------------- xg GEMM: C[M,1536] = A[M,512] * Bt[1536,512]^T, bf16 in, bf16 out ----------------

__global__ __launch_bounds__(256) void k_gemm(const u16* __restrict__ A,
                                              const u16* __restrict__ Bt,
                                              u16* __restrict__ C) {
  __shared__ u16 As[128 * 40];
  __shared__ u16 Bs[128 * 40];
  int m0 = blockIdx.x * 128, n0 = blockIdx.y * 128;
  int tid = threadIdx.x, lane = tid & 63, w = tid >> 6, wr = w >> 1, wc = w & 1;
  int rl = lane & 15, kq = lane >> 4;
  v4f acc[4][4] = {};
  for (int k0 = 0; k0 < 512; k0 += 32) {
#pragma unroll
    for (int c = tid; c < 1024; c += 256) {
      int row = (c & 511) >> 2, q = c & 3;
      const u16* src = (c < 512) ? (A + (size_t)(m0 + row) * 512 + k0 + q * 8)
                                 : (Bt + (size_t)(n0 + row) * 512 + k0 + q * 8);
      uint4 v = *reinterpret_cast<const uint4*>(src);
      u16* dst = (c < 512) ? (As + row * 40 + q * 8) : (Bs + row * 40 + q * 8);
      *reinterpret_cast<uint4*>(dst) = v;
    }
    __syncthreads();
    v8bf a[4], b[4];
#pragma unroll
    for (int mi = 0; mi < 4; ++mi)
      a[mi] = *reinterpret_cast<const v8bf*>(As + (wr * 64 + mi * 16 + rl) * 40 + kq * 8);
#pragma unroll
    for (int ni = 0; ni < 4; ++ni)
      b[ni] = *reinterpret_cast<const v8bf*>(Bs + (wc * 64 + ni * 16 + rl) * 40 + kq * 8);
#pragma unroll
    for (int mi = 0; mi < 4; ++mi)
#pragma unroll
      for (int ni = 0; ni < 4; ++ni)
        acc[mi][ni] = __builtin_amdgcn_mfma_f32_16x16x32_bf16(a[mi], b[ni], acc[mi][ni], 0, 0, 0);
    __syncthreads();
  }
#pragma unroll
  for (int mi = 0; mi < 4; ++mi)
#pragma unroll
    for (int ni = 0; ni < 4; ++ni)
#pragma unroll
      for (int r = 0; r < 4; ++r) {
        int row = m0 + wr * 64 + mi * 16 + kq * 4 + r;
        int col = n0 + wc * 64 + ni * 16 + rl;
        C[(size_t)row * G3 + col] = f2b(acc[mi][ni][r]);
      }
}

// ---------------- persistent recurrence kernel (one layer) ----------------
// grid = 128 blocks: group g = blk>>5 (16 batch rows), slice s = blk&31 (16 h-cols).
// LDS: [0,114688) packed weights, [114688,147712) A-buf 16x1032 bf16 (padded), [147712,151808) gate stage f32.

__global__ __launch_bounds__(256, 1) void k_lstm(
    const u16* __restrict__ xg, const u16* __restrict__ wp,
    const float* __restrict__ biasf, const float* __restrict__ bhh,
    const float* __restrict__ xin_f32, const u16* __restrict__ xin_bf16,
    u16* __restrict__ outs_bf16, float* __restrict__ outs_f32,
    float* __restrict__ hn, float* __restrict__ cn,
    u16* __restrict__ hc, u32* __restrict__ cnt) {
  extern __shared__ char lds[];
  u16* wlds = (u16*)lds;
  u16* alds = (u16*)(lds + 114688);
  float* olds = (float*)(lds + 114688 + 33024);
  int tid = threadIdx.x, lane = tid & 63, w = tid >> 6;
  int blk = blockIdx.x, g = blk >> 5, s = blk & 31;

  // one-time: weights slice -> LDS
  const u16* wsrc = wp + (size_t)s * 57344;
  for (int i = tid; i < 7168; i += 256)
    reinterpret_cast<uint4*>(wlds)[i] = reinterpret_cast<const uint4*>(wsrc)[i];

  int erow = tid >> 4, ecol = tid & 15;          // elementwise ownership (b-row, h-col)
  int bglob = g * 16 + erow, hcol = s * 16 + ecol;
  int col16 = lane & 15, kq = lane >> 4;
  float bias_w;
  int cbase;
  if (w < 3) { bias_w = biasf[w * 512 + s * 16 + col16]; cbase = w * 32; }
  else       { bias_w = bhh[s * 16 + col16];             cbase = 96; }
  int colglob = w * 512 + s * 16 + col16;        // gate waves only
  float c_reg = 0.0f;
  __syncthreads();

  for (int t = 0; t < T_STEPS; ++t) {
    // stage A = [h(512) | c(512)] for this group, bf16, padded rows (1032 elems)
    const u16* hsrc = hc + (size_t)((t & 1) * 4 + g) * 16384;
#pragma unroll
    for (int i = tid; i < 2048; i += 256) {
      int row = i >> 7, q = i & 127;
      *reinterpret_cast<uint4*>(alds + row * 1032 + q * 8) =
          *reinterpret_cast<const uint4*>(hsrc + row * 1024 + q * 8);
    }
    __syncthreads();

    v4f acc;
    if (w < 3) {
      const u16* xgp = xg + (size_t)(t * 64 + g * 16 + kq * 4) * G3 + colglob;
#pragma unroll
      for (int r = 0; r < 4; ++r) acc[r] = b2f(xgp[(size_t)r * G3]) + bias_w;
#pragma unroll
      for (int kk = 0; kk < 32; ++kk) {
        v8bf a = *reinterpret_cast<const v8bf*>(alds + col16 * 1032 + kk * 32 + kq * 8);
        v8bf b = *reinterpret_cast<const v8bf*>(wlds + (cbase + kk) * 512 + lane * 8);
        acc = __builtin_amdgcn_mfma_f32_16x16x32_bf16(a, b, acc, 0, 0, 0);
      }
    } else {
#pragma unroll
      for (int r = 0; r < 4; ++r) acc[r] = bias_w;
#pragma unroll
      for (int kk = 0; kk < 16; ++kk) {
        v8bf a = *reinterpret_cast<const v8bf*>(alds + col16 * 1032 + kk * 32 + kq * 8);
        v8bf b = *reinterpret_cast<const v8bf*>(wlds + (cbase + kk) * 512 + lane * 8);
        acc = __builtin_amdgcn_mfma_f32_16x16x32_bf16(a, b, acc, 0, 0, 0);
      }
    }

    // stage the 4 [16,16] tiles (i,f,o,cell) to LDS, f32
#pragma unroll
    for (int r = 0; r < 4; ++r) olds[w * 256 + (kq * 4 + r) * 16 + col16] = acc[r];
    __syncthreads();

    // elementwise: thread owns (erow, ecol)
    float gi = olds[tid], gf = olds[256 + tid], go = olds[512 + tid], gg = olds[768 + tid];
    float xi = xin_f32 ? xin_f32[(size_t)(t * 64 + bglob) * 512 + hcol]
                       : b2f(xin_bf16[(size_t)(t * 64 + bglob) * 512 + hcol]);
    float i_s = sigm(gi), f_s = sigm(gf), o_s = sigm(go);
    float cg = tanhf(gg);
    float cy = f_s * c_reg + i_s * cg;
    float hy = o_s * (tanhf(cy) + xi);
    c_reg = cy;

    u16 hyb = f2b(hy), cyb = f2b(cy);
    u16* hdst = hc + (size_t)(((t + 1) & 1) * 4 + g) * 16384;
    hdst[erow * 1024 + hcol] = hyb;
    hdst[erow * 1024 + 512 + hcol] = cyb;
    if (outs_bf16) outs_bf16[(size_t)(t * 64 + bglob) * 512 + hcol] = hyb;
    if (outs_f32)  outs_f32[(size_t)(t * 64 + bglob) * 512 + hcol] = hy;
    if (t == T_STEPS - 1) {
      hn[bglob * 512 + hcol] = hy;
      cn[bglob * 512 + hcol] = cy;
    }
    __syncthreads();

    // group barrier (32 blocks), agent-scope release/acquire for cross-XCD visibility
    if (t < T_STEPS - 1) {
      if (tid == 0) {
        __hip_atomic_fetch_add(cnt + g * 64, 1u, __ATOMIC_RELEASE, __HIP_MEMORY_SCOPE_AGENT);
        u32 target = 32u * (u32)(t + 1);
        while (__hip_atomic_load(cnt + g * 64, __ATOMIC_ACQUIRE, __HIP_MEMORY_SCOPE_AGENT) < target)
          __builtin_amdgcn_s_sleep(2);
      }
      __syncthreads();
    }
  }
}

// ---------------- launch ----------------

extern "C" void kernel_launch(void* const* d_in, const int* in_sizes, int n_in,
                              void* d_out, int out_size, void* d_ws, size_t ws_size,
                              hipStream_t stream) {
  const float* x   = (const float*)d_in[0];
  const float* Wii = (const float*)d_in[1];
  const float* Wic = (const float*)d_in[2];
  const float* Wih = (const float*)d_in[3];
  const float* bii = (const float*)d_in[4];
  const float* bic = (const float*)d_in[5];
  const float* bih = (const float*)d_in[6];
  const float* Whh = (const float*)d_in[7];
  const float* bhh = (const float*)d_in[8];
  float* out = (float*)d_out;
  char* ws = (char*)d_ws;

  u16* xbf    = (u16*)(ws + OFF_XBF);
  u16* outs1  = (u16*)(ws + OFF_OUTS1);
  u16* xgb    = (u16*)(ws + OFF_XG);
  u16* wiib   = (u16*)(ws + OFF_WII);
  u16* wpack  = (u16*)(ws + OFF_WPACK);
  float* biasf = (float*)(ws + OFF_BIASF);
  u16* hc     = (u16*)(ws + OFF_HC);
  u32* cnt    = (u32*)(ws + OFF_CNT);

  hipFuncSetAttribute(reinterpret_cast<const void*>(k_lstm),
                      hipFuncAttributeMaxDynamicSharedMemorySize, 151808);

  // prep: bf16 conversions, bias fold, weight packing
  k_cvt <<<2048, 256, 0, stream>>>(x, xbf, 33554432 / 4);
  k_cvt <<<1536, 256, 0, stream>>>(Wii, wiib, 1572864 / 4);
  k_fold<<<12, 256, 0, stream>>>(bii, bic, bih, biasf, 3072);
  k_pack<<<1792, 256, 0, stream>>>(Wih, Wic, Whh, wpack);

  float* hn = out + 33554432;
  float* cn = out + 33554432 + 65536;

  for (int l = 0; l < 2; ++l) {
    hipMemsetAsync(ws + OFF_HC, 0, 262144 + 1024, stream);  // zero h0/c0 + barrier counters
    k_gemm<<<dim3(512, 12), 256, 0, stream>>>(l ? outs1 : xbf,
                                              wiib + (size_t)l * 786432, xgb);
    k_lstm<<<128, 256, 151808, stream>>>(
        xgb, wpack + (size_t)l * 1835008,
        biasf + l * 1536, bhh + l * 512,
        l ? nullptr : x, l ? outs1 : nullptr,
        l ? nullptr : outs1, l ? out : nullptr,
        hn + l * 32768, cn + l * 32768,
        hc, cnt);
  }
}

// Round 2
// 7658.674 us; speedup vs baseline: 2.4321x; 2.4321x over previous
//
#include <hip/hip_runtime.h>
#include <cstdint>

typedef unsigned short u16;
typedef unsigned int   u32;
typedef __bf16 v8bf __attribute__((ext_vector_type(8)));
typedef float  v4f  __attribute__((ext_vector_type(4)));
typedef u32    u32x4 __attribute__((ext_vector_type(4)));

#define T_STEPS 1024
#define G3 1536

// ws layout (bytes). Total ~330.3 MB.
#define OFF_XBF   0ull          // x bf16               [65536,512]   67,108,864
#define OFF_OUTS1 67108864ull   // layer-1 outs bf16    [65536,512]   67,108,864
#define OFF_XG    134217728ull  // xg bf16              [65536,1536] 201,326,592
#define OFF_WII   335544320ull  // Wii bf16             [2,1536,512]   3,145,728
#define OFF_WPACK 338690048ull  // packed B-frag weights              7,340,032
#define OFF_BIASF 346030080ull  // folded gate bias f32 [2,1536]          12,288
#define OFF_HC    346042368ull  // h/c ping-pong bf16 [2][4][16][1024]  262,144
#define OFF_CNT   346304512ull  // 4 group counters, 256B apart           1,024

__device__ __forceinline__ u16 f2b(float f) {
  u32 u = __builtin_bit_cast(u32, f);
  u += 0x7fffu + ((u >> 16) & 1u);
  return (u16)(u >> 16);
}
__device__ __forceinline__ float b2f(u16 h) {
  u32 u = ((u32)h) << 16;
  return __builtin_bit_cast(float, u);
}
__device__ __forceinline__ float sigm(float x) { return 1.0f / (1.0f + __expf(-x)); }

// L3-coherent (bypass L1/L2) primitives for cross-XCD h/c exchange.
__device__ __forceinline__ void store_short_l3(void* p, u32 v) {
  asm volatile("global_store_short %0, %1, off sc0 sc1" :: "v"(p), "v"(v) : "memory");
}
__device__ __forceinline__ u32 load_dword_l3(const void* p) {
  u32 v;
  asm volatile("global_load_dword %0, %1, off sc0 sc1\n\ts_waitcnt vmcnt(0)"
               : "=v"(v) : "v"(p) : "memory");
  return v;
}

// ---------------- prep kernels ----------------

__global__ void k_cvt(const float* __restrict__ s, u16* __restrict__ d, int n4) {
  int i = blockIdx.x * blockDim.x + threadIdx.x;
  int st = gridDim.x * blockDim.x;
  for (; i < n4; i += st) {
    float4 v = reinterpret_cast<const float4*>(s)[i];
    u32 lo = (u32)f2b(v.x) | ((u32)f2b(v.y) << 16);
    u32 hi = (u32)f2b(v.z) | ((u32)f2b(v.w) << 16);
    uint2 pk; pk.x = lo; pk.y = hi;
    reinterpret_cast<uint2*>(d)[i] = pk;
  }
}

__global__ void k_fold(const float* __restrict__ a, const float* __restrict__ b,
                       const float* __restrict__ c, float* __restrict__ o, int n) {
  int i = blockIdx.x * blockDim.x + threadIdx.x;
  if (i < n) o[i] = a[i] + b[i] + c[i];
}

// Pack recurrent weights into MFMA B-fragment order, bf16.
__global__ void k_pack(const float* __restrict__ Wih, const float* __restrict__ Wic,
                       const float* __restrict__ Whh, u16* __restrict__ wp) {
  int t = blockIdx.x * blockDim.x + threadIdx.x;
  if (t >= 2 * 32 * 112 * 64) return;
  int lane = t & 63; int rest = t >> 6;
  int c = rest % 112; rest /= 112;
  int s = rest & 31; int l = rest >> 5;
  int col16 = lane & 15, kq = lane >> 4;
  const float* src;
  if (c < 96) {
    int tau = c >> 5, kk = c & 31;
    int col = tau * 512 + s * 16 + col16;
    int k = kk * 32 + kq * 8;
    src = (k < 512) ? (Wih + ((size_t)l * G3 + col) * 512 + k)
                    : (Wic + ((size_t)l * G3 + col) * 512 + (k - 512));
  } else {
    int kk = c - 96;
    int col = s * 16 + col16;
    int k = kk * 32 + kq * 8;
    src = Whh + ((size_t)l * 512 + col) * 512 + k;
  }
  u16 o[8];
#pragma unroll
  for (int i = 0; i < 8; ++i) o[i] = f2b(src[i]);
  uint4 v;
  v.x = (u32)o[0] | ((u32)o[1] << 16);
  v.y = (u32)o[2] | ((u32)o[3] << 16);
  v.z = (u32)o[4] | ((u32)o[5] << 16);
  v.w = (u32)o[6] | ((u32)o[7] << 16);
  reinterpret_cast<uint4*>(wp)[t] = v;
}

// ---------------- xg GEMM: C[M,1536] = A[M,512] * Bt[1536,512]^T ----------------

__global__ __launch_bounds__(256) void k_gemm(const u16* __restrict__ A,
                                              const u16* __restrict__ Bt,
                                              u16* __restrict__ C) {
  __shared__ u16 As[128 * 40];
  __shared__ u16 Bs[128 * 40];
  int m0 = blockIdx.x * 128, n0 = blockIdx.y * 128;
  int tid = threadIdx.x, lane = tid & 63, w = tid >> 6, wr = w >> 1, wc = w & 1;
  int rl = lane & 15, kq = lane >> 4;
  v4f acc[4][4] = {};
  for (int k0 = 0; k0 < 512; k0 += 32) {
#pragma unroll
    for (int c = tid; c < 1024; c += 256) {
      int row = (c & 511) >> 2, q = c & 3;
      const u16* src = (c < 512) ? (A + (size_t)(m0 + row) * 512 + k0 + q * 8)
                                 : (Bt + (size_t)(n0 + row) * 512 + k0 + q * 8);
      uint4 v = *reinterpret_cast<const uint4*>(src);
      u16* dst = (c < 512) ? (As + row * 40 + q * 8) : (Bs + row * 40 + q * 8);
      *reinterpret_cast<uint4*>(dst) = v;
    }
    __syncthreads();
    v8bf a[4], b[4];
#pragma unroll
    for (int mi = 0; mi < 4; ++mi)
      a[mi] = *reinterpret_cast<const v8bf*>(As + (wr * 64 + mi * 16 + rl) * 40 + kq * 8);
#pragma unroll
    for (int ni = 0; ni < 4; ++ni)
      b[ni] = *reinterpret_cast<const v8bf*>(Bs + (wc * 64 + ni * 16 + rl) * 40 + kq * 8);
#pragma unroll
    for (int mi = 0; mi < 4; ++mi)
#pragma unroll
      for (int ni = 0; ni < 4; ++ni)
        acc[mi][ni] = __builtin_amdgcn_mfma_f32_16x16x32_bf16(a[mi], b[ni], acc[mi][ni], 0, 0, 0);
    __syncthreads();
  }
#pragma unroll
  for (int mi = 0; mi < 4; ++mi)
#pragma unroll
    for (int ni = 0; ni < 4; ++ni)
#pragma unroll
      for (int r = 0; r < 4; ++r) {
        int row = m0 + wr * 64 + mi * 16 + kq * 4 + r;
        int col = n0 + wc * 64 + ni * 16 + rl;
        C[(size_t)row * G3 + col] = f2b(acc[mi][ni][r]);
      }
}

// ---------------- persistent recurrence kernel (one layer) ----------------
// grid = 128 blocks: group g = blk>>5 (16 batch rows), slice s = blk&31 (16 h-cols).
// Barrier: plain device-scope atomicAdd counter (L3-coherent) + sc0/sc1 poll load.
// h/c exchange: sc0/sc1 stores/loads straight to/from L3 — NO acquire/release fences,
// so no per-step L1/L2 invalidate or L2 writeback.

__global__ __launch_bounds__(256, 1) void k_lstm(
    const u16* __restrict__ xg, const u16* __restrict__ wp,
    const float* __restrict__ biasf, const float* __restrict__ bhh,
    const float* __restrict__ xin_f32, const u16* __restrict__ xin_bf16,
    u16* __restrict__ outs_bf16, float* __restrict__ outs_f32,
    float* __restrict__ hn, float* __restrict__ cn,
    u16* __restrict__ hc, u32* __restrict__ cnt) {
  extern __shared__ char lds[];
  u16* wlds = (u16*)lds;
  u16* alds = (u16*)(lds + 114688);
  float* olds = (float*)(lds + 114688 + 33024);
  int tid = threadIdx.x, lane = tid & 63, w = tid >> 6;
  int blk = blockIdx.x, g = blk >> 5, s = blk & 31;
  u32* cptr = cnt + g * 64;

  // one-time: weights slice -> LDS
  const u16* wsrc = wp + (size_t)s * 57344;
  for (int i = tid; i < 7168; i += 256)
    reinterpret_cast<uint4*>(wlds)[i] = reinterpret_cast<const uint4*>(wsrc)[i];

  int erow = tid >> 4, ecol = tid & 15;          // elementwise ownership (b-row, h-col)
  int bglob = g * 16 + erow, hcol = s * 16 + ecol;
  int col16 = lane & 15, kq = lane >> 4;
  float bias_w;
  int cbase;
  if (w < 3) { bias_w = biasf[w * 512 + s * 16 + col16]; cbase = w * 32; }
  else       { bias_w = bhh[s * 16 + col16];             cbase = 96; }
  int colglob = w * 512 + s * 16 + col16;        // gate waves only
  float c_reg = 0.0f;
  __syncthreads();

  for (int t = 0; t < T_STEPS; ++t) {
    // ---- prefetch per-step read-only data BEFORE the barrier (hides latency) ----
    float seed[4];
    if (w < 3) {
      const u16* xgp = xg + (size_t)(t * 64 + g * 16 + kq * 4) * G3 + colglob;
#pragma unroll
      for (int r = 0; r < 4; ++r) seed[r] = b2f(xgp[(size_t)r * G3]) + bias_w;
    } else {
#pragma unroll
      for (int r = 0; r < 4; ++r) seed[r] = bias_w;
    }
    float xi = xin_f32 ? xin_f32[(size_t)(t * 64 + bglob) * 512 + hcol]
                       : b2f(xin_bf16[(size_t)(t * 64 + bglob) * 512 + hcol]);

    // ---- group barrier wait (fence-free) ----
    if (t > 0) {
      if (tid == 0) {
        u32 target = 32u * (u32)t;
        u32 v = load_dword_l3(cptr);
        while (v < target) {
          __builtin_amdgcn_s_sleep(1);
          v = load_dword_l3(cptr);
        }
      }
      __syncthreads();
    }

    // ---- stage A = [h(512) | c(512)] for this group via L3-coherent loads ----
    const u16* hsrc = hc + (size_t)((t & 1) * 4 + g) * 16384;
    u32x4 r8[8];
#pragma unroll
    for (int i = 0; i < 8; ++i) {
      int idx = tid + i * 256;
      const void* p = hsrc + (idx >> 7) * 1024 + (idx & 127) * 8;
      asm volatile("global_load_dwordx4 %0, %1, off sc0 sc1" : "=v"(r8[i]) : "v"(p) : "memory");
    }
    asm volatile("s_waitcnt vmcnt(0)" ::: "memory");
    __builtin_amdgcn_sched_barrier(0);
#pragma unroll
    for (int i = 0; i < 8; ++i) {
      int idx = tid + i * 256;
      *reinterpret_cast<u32x4*>(alds + (idx >> 7) * 1032 + (idx & 127) * 8) = r8[i];
    }
    __syncthreads();

    // ---- MFMA: 4 independent accumulator chains ----
    auto Af = [&](int kk) {
      return *reinterpret_cast<const v8bf*>(alds + col16 * 1032 + kk * 32 + kq * 8);
    };
    auto Bf = [&](int kk) {
      return *reinterpret_cast<const v8bf*>(wlds + (cbase + kk) * 512 + lane * 8);
    };
    v4f ac0, ac1, ac2, ac3;
#pragma unroll
    for (int r = 0; r < 4; ++r) { ac0[r] = seed[r]; ac1[r] = 0.f; ac2[r] = 0.f; ac3[r] = 0.f; }
    if (w < 3) {
#pragma unroll
      for (int kk = 0; kk < 32; kk += 4) {
        ac0 = __builtin_amdgcn_mfma_f32_16x16x32_bf16(Af(kk + 0), Bf(kk + 0), ac0, 0, 0, 0);
        ac1 = __builtin_amdgcn_mfma_f32_16x16x32_bf16(Af(kk + 1), Bf(kk + 1), ac1, 0, 0, 0);
        ac2 = __builtin_amdgcn_mfma_f32_16x16x32_bf16(Af(kk + 2), Bf(kk + 2), ac2, 0, 0, 0);
        ac3 = __builtin_amdgcn_mfma_f32_16x16x32_bf16(Af(kk + 3), Bf(kk + 3), ac3, 0, 0, 0);
      }
    } else {
#pragma unroll
      for (int kk = 0; kk < 16; kk += 4) {
        ac0 = __builtin_amdgcn_mfma_f32_16x16x32_bf16(Af(kk + 0), Bf(kk + 0), ac0, 0, 0, 0);
        ac1 = __builtin_amdgcn_mfma_f32_16x16x32_bf16(Af(kk + 1), Bf(kk + 1), ac1, 0, 0, 0);
        ac2 = __builtin_amdgcn_mfma_f32_16x16x32_bf16(Af(kk + 2), Bf(kk + 2), ac2, 0, 0, 0);
        ac3 = __builtin_amdgcn_mfma_f32_16x16x32_bf16(Af(kk + 3), Bf(kk + 3), ac3, 0, 0, 0);
      }
    }
    v4f acc;
#pragma unroll
    for (int r = 0; r < 4; ++r) acc[r] = (ac0[r] + ac1[r]) + (ac2[r] + ac3[r]);

    // ---- stage the 4 [16,16] tiles (i,f,o,cell) to LDS, f32 ----
#pragma unroll
    for (int r = 0; r < 4; ++r) olds[w * 256 + (kq * 4 + r) * 16 + col16] = acc[r];
    __syncthreads();

    // ---- elementwise: thread owns (erow, ecol) ----
    float gi = olds[tid], gf = olds[256 + tid], go = olds[512 + tid], gg = olds[768 + tid];
    float i_s = sigm(gi), f_s = sigm(gf), o_s = sigm(go);
    float cg = tanhf(gg);
    float cy = f_s * c_reg + i_s * cg;
    float hy = o_s * (tanhf(cy) + xi);
    c_reg = cy;

    u16 hyb = f2b(hy), cyb = f2b(cy);
    u16* hdst = hc + (size_t)(((t + 1) & 1) * 4 + g) * 16384;
    store_short_l3(hdst + erow * 1024 + hcol, (u32)hyb);
    store_short_l3(hdst + erow * 1024 + 512 + hcol, (u32)cyb);
    asm volatile("s_waitcnt vmcnt(0)" ::: "memory");
    __syncthreads();  // all threads' h/c committed to L3

    // ---- arrive, then do the slow HBM outs stores off the critical path ----
    if (t < T_STEPS - 1 && tid == 0) atomicAdd(cptr, 1u);

    if (outs_bf16) outs_bf16[(size_t)(t * 64 + bglob) * 512 + hcol] = hyb;
    if (outs_f32)  outs_f32[(size_t)(t * 64 + bglob) * 512 + hcol] = hy;
    if (t == T_STEPS - 1) {
      hn[bglob * 512 + hcol] = hy;
      cn[bglob * 512 + hcol] = cy;
    }
  }
}

// ---------------- launch ----------------

extern "C" void kernel_launch(void* const* d_in, const int* in_sizes, int n_in,
                              void* d_out, int out_size, void* d_ws, size_t ws_size,
                              hipStream_t stream) {
  const float* x   = (const float*)d_in[0];
  const float* Wii = (const float*)d_in[1];
  const float* Wic = (const float*)d_in[2];
  const float* Wih = (const float*)d_in[3];
  const float* bii = (const float*)d_in[4];
  const float* bic = (const float*)d_in[5];
  const float* bih = (const float*)d_in[6];
  const float* Whh = (const float*)d_in[7];
  const float* bhh = (const float*)d_in[8];
  float* out = (float*)d_out;
  char* ws = (char*)d_ws;

  u16* xbf    = (u16*)(ws + OFF_XBF);
  u16* outs1  = (u16*)(ws + OFF_OUTS1);
  u16* xgb    = (u16*)(ws + OFF_XG);
  u16* wiib   = (u16*)(ws + OFF_WII);
  u16* wpack  = (u16*)(ws + OFF_WPACK);
  float* biasf = (float*)(ws + OFF_BIASF);
  u16* hc     = (u16*)(ws + OFF_HC);
  u32* cnt    = (u32*)(ws + OFF_CNT);

  hipFuncSetAttribute(reinterpret_cast<const void*>(k_lstm),
                      hipFuncAttributeMaxDynamicSharedMemorySize, 151808);

  // prep: bf16 conversions, bias fold, weight packing
  k_cvt <<<2048, 256, 0, stream>>>(x, xbf, 33554432 / 4);
  k_cvt <<<1536, 256, 0, stream>>>(Wii, wiib, 1572864 / 4);
  k_fold<<<12, 256, 0, stream>>>(bii, bic, bih, biasf, 3072);
  k_pack<<<1792, 256, 0, stream>>>(Wih, Wic, Whh, wpack);

  float* hn = out + 33554432;
  float* cn = out + 33554432 + 65536;

  for (int l = 0; l < 2; ++l) {
    hipMemsetAsync(ws + OFF_HC, 0, 262144 + 1024, stream);  // zero h0/c0 + barrier counters
    k_gemm<<<dim3(512, 12), 256, 0, stream>>>(l ? outs1 : xbf,
                                              wiib + (size_t)l * 786432, xgb);
    k_lstm<<<128, 256, 151808, stream>>>(
        xgb, wpack + (size_t)l * 1835008,
        biasf + l * 1536, bhh + l * 512,
        l ? nullptr : x, l ? outs1 : nullptr,
        l ? nullptr : outs1, l ? out : nullptr,
        hn + l * 32768, cn + l * 32768,
        hc, cnt);
  }
}

// Round 3
// 7096.355 us; speedup vs baseline: 2.6248x; 1.0792x over previous
//
#include <hip/hip_runtime.h>
#include <cstdint>

typedef unsigned short u16;
typedef unsigned int   u32;
typedef __bf16 v8bf  __attribute__((ext_vector_type(8)));
typedef float  v4f   __attribute__((ext_vector_type(4)));
typedef u32    u32x2 __attribute__((ext_vector_type(2)));
typedef u32    u32x4 __attribute__((ext_vector_type(4)));

#define T_STEPS 1024
#define G3 1536

// ws layout (bytes). hc tag-buffer OVERLAPS the head of xbf (dead after k_gemm
// of each layer; memset is issued after k_gemm, before k_lstm).
#define OFF_HC    0ull          // tagged h/c ping-pong [2][4][16][512] uint2 = 524,288
#define OFF_XBF   0ull          // x bf16               [65536,512]   67,108,864
#define OFF_OUTS1 67108864ull   // layer-1 outs bf16    [65536,512]   67,108,864
#define OFF_XG    134217728ull  // xg bf16              [65536,1536] 201,326,592
#define OFF_WII   335544320ull  // Wii bf16             [2,1536,512]   3,145,728
#define OFF_WPACK 338690048ull  // packed B-frag weights              7,340,032
#define OFF_BIASF 346030080ull  // folded gate bias f32 [2,1536]          12,288

__device__ __forceinline__ u16 f2b(float f) {
  u32 u = __builtin_bit_cast(u32, f);
  u += 0x7fffu + ((u >> 16) & 1u);
  return (u16)(u >> 16);
}
__device__ __forceinline__ float b2f(u16 h) {
  u32 u = ((u32)h) << 16;
  return __builtin_bit_cast(float, u);
}
__device__ __forceinline__ float sigm(float x) { return 1.0f / (1.0f + __expf(-x)); }

// ---------------- prep kernels ----------------

__global__ void k_cvt(const float* __restrict__ s, u16* __restrict__ d, int n4) {
  int i = blockIdx.x * blockDim.x + threadIdx.x;
  int st = gridDim.x * blockDim.x;
  for (; i < n4; i += st) {
    float4 v = reinterpret_cast<const float4*>(s)[i];
    u32 lo = (u32)f2b(v.x) | ((u32)f2b(v.y) << 16);
    u32 hi = (u32)f2b(v.z) | ((u32)f2b(v.w) << 16);
    uint2 pk; pk.x = lo; pk.y = hi;
    reinterpret_cast<uint2*>(d)[i] = pk;
  }
}

__global__ void k_fold(const float* __restrict__ a, const float* __restrict__ b,
                       const float* __restrict__ c, float* __restrict__ o, int n) {
  int i = blockIdx.x * blockDim.x + threadIdx.x;
  if (i < n) o[i] = a[i] + b[i] + c[i];
}

// Pack recurrent weights into MFMA B-fragment order, bf16.
// [l][s][chunk c][lane][8]; c<96: gates tau=c>>5, kk=c&31 (K=1024: k<512 Wih, k>=512 Wic)
// c>=96: cellgate (Whh), kk=c-96 (K=512). B[k][col]=W[col][k].
__global__ void k_pack(const float* __restrict__ Wih, const float* __restrict__ Wic,
                       const float* __restrict__ Whh, u16* __restrict__ wp) {
  int t = blockIdx.x * blockDim.x + threadIdx.x;
  if (t >= 2 * 32 * 112 * 64) return;
  int lane = t & 63; int rest = t >> 6;
  int c = rest % 112; rest /= 112;
  int s = rest & 31; int l = rest >> 5;
  int col16 = lane & 15, kq = lane >> 4;
  const float* src;
  if (c < 96) {
    int tau = c >> 5, kk = c & 31;
    int col = tau * 512 + s * 16 + col16;
    int k = kk * 32 + kq * 8;
    src = (k < 512) ? (Wih + ((size_t)l * G3 + col) * 512 + k)
                    : (Wic + ((size_t)l * G3 + col) * 512 + (k - 512));
  } else {
    int kk = c - 96;
    int col = s * 16 + col16;
    int k = kk * 32 + kq * 8;
    src = Whh + ((size_t)l * 512 + col) * 512 + k;
  }
  u16 o[8];
#pragma unroll
  for (int i = 0; i < 8; ++i) o[i] = f2b(src[i]);
  uint4 v;
  v.x = (u32)o[0] | ((u32)o[1] << 16);
  v.y = (u32)o[2] | ((u32)o[3] << 16);
  v.z = (u32)o[4] | ((u32)o[5] << 16);
  v.w = (u32)o[6] | ((u32)o[7] << 16);
  reinterpret_cast<uint4*>(wp)[t] = v;
}

// ---------------- xg GEMM: C[M,1536] = A[M,512] * Bt[1536,512]^T ----------------

__global__ __launch_bounds__(256) void k_gemm(const u16* __restrict__ A,
                                              const u16* __restrict__ Bt,
                                              u16* __restrict__ C) {
  __shared__ u16 As[128 * 40];
  __shared__ u16 Bs[128 * 40];
  int m0 = blockIdx.x * 128, n0 = blockIdx.y * 128;
  int tid = threadIdx.x, lane = tid & 63, w = tid >> 6, wr = w >> 1, wc = w & 1;
  int rl = lane & 15, kq = lane >> 4;
  v4f acc[4][4] = {};
  for (int k0 = 0; k0 < 512; k0 += 32) {
#pragma unroll
    for (int c = tid; c < 1024; c += 256) {
      int row = (c & 511) >> 2, q = c & 3;
      const u16* src = (c < 512) ? (A + (size_t)(m0 + row) * 512 + k0 + q * 8)
                                 : (Bt + (size_t)(n0 + row) * 512 + k0 + q * 8);
      uint4 v = *reinterpret_cast<const uint4*>(src);
      u16* dst = (c < 512) ? (As + row * 40 + q * 8) : (Bs + row * 40 + q * 8);
      *reinterpret_cast<uint4*>(dst) = v;
    }
    __syncthreads();
    v8bf a[4], b[4];
#pragma unroll
    for (int mi = 0; mi < 4; ++mi)
      a[mi] = *reinterpret_cast<const v8bf*>(As + (wr * 64 + mi * 16 + rl) * 40 + kq * 8);
#pragma unroll
    for (int ni = 0; ni < 4; ++ni)
      b[ni] = *reinterpret_cast<const v8bf*>(Bs + (wc * 64 + ni * 16 + rl) * 40 + kq * 8);
#pragma unroll
    for (int mi = 0; mi < 4; ++mi)
#pragma unroll
      for (int ni = 0; ni < 4; ++ni)
        acc[mi][ni] = __builtin_amdgcn_mfma_f32_16x16x32_bf16(a[mi], b[ni], acc[mi][ni], 0, 0, 0);
    __syncthreads();
  }
#pragma unroll
  for (int mi = 0; mi < 4; ++mi)
#pragma unroll
    for (int ni = 0; ni < 4; ++ni)
#pragma unroll
      for (int r = 0; r < 4; ++r) {
        int row = m0 + wr * 64 + mi * 16 + kq * 4 + r;
        int col = n0 + wc * 64 + ni * 16 + rl;
        C[(size_t)row * G3 + col] = f2b(acc[mi][ni][r]);
      }
}

// ---------------- persistent recurrence kernel (one layer) ----------------
// grid = 128 blocks: group g = blk>>5 (16 batch rows), slice s = blk&31 (16 h-cols).
// Exchange: tagged 8B packets {h|c<<16, step_tag} via sc0/sc1 (L3). The tag check
// IS the barrier — no fences, no atomics, no producer-side waits.
// Weights live in registers (step-invariant B fragments).

__global__ __launch_bounds__(256, 1) void k_lstm(
    const u16* __restrict__ xg, const u16* __restrict__ wp,
    const float* __restrict__ biasf, const float* __restrict__ bhh,
    const float* __restrict__ xin_f32, const u16* __restrict__ xin_bf16,
    u16* __restrict__ outs_bf16, float* __restrict__ outs_f32,
    float* __restrict__ hn, float* __restrict__ cn,
    u32x2* __restrict__ hc) {
  __shared__ u16 alds[16 * 1032];   // [16 rows][h(512) | c(512)] padded to 1032
  __shared__ float olds[1024];      // 4 gate tiles [16][16] f32
  int tid = threadIdx.x, lane = tid & 63, w = tid >> 6;
  int blk = blockIdx.x, g = blk >> 5, s = blk & 31;

  int erow = tid >> 4, ecol = tid & 15;          // elementwise ownership
  int bglob = g * 16 + erow, hcol = s * 16 + ecol;
  int col16 = lane & 15, kq = lane >> 4;
  float bias_w; int cbase;
  if (w < 3) { bias_w = biasf[w * 512 + s * 16 + col16]; cbase = w * 32; }
  else       { bias_w = bhh[s * 16 + col16];             cbase = 96; }
  int colglob = w * 512 + s * 16 + col16;

  // one-time: B fragments -> registers (128 VGPR for gate waves, 64 for cell wave)
  const u16* wsrc = wp + (size_t)s * 57344 + (size_t)cbase * 512 + lane * 8;
  v8bf breg[32];
  if (w < 3) {
#pragma unroll
    for (int kk = 0; kk < 32; ++kk)
      breg[kk] = *reinterpret_cast<const v8bf*>(wsrc + kk * 512);
  } else {
#pragma unroll
    for (int kk = 0; kk < 16; ++kk)
      breg[kk] = *reinterpret_cast<const v8bf*>(wsrc + kk * 512);
  }

  float c_reg = 0.0f;

  for (int t = 0; t < T_STEPS; ++t) {
    // ---- prefetch per-step read-only data (overlaps the poll) ----
    float seed[4];
    if (w < 3) {
      const u16* xgp = xg + (size_t)(t * 64 + g * 16 + kq * 4) * G3 + colglob;
#pragma unroll
      for (int r = 0; r < 4; ++r) seed[r] = b2f(xgp[(size_t)r * G3]) + bias_w;
    } else {
#pragma unroll
      for (int r = 0; r < 4; ++r) seed[r] = bias_w;
    }
    float xi = xin_f32 ? xin_f32[(size_t)(t * 64 + bglob) * 512 + hcol]
                       : b2f(xin_bf16[(size_t)(t * 64 + bglob) * 512 + hcol]);

    // ---- poll-load tagged h/c: 4096 dwordx4 packets per group, 16 per thread ----
    const char* bufr = (const char*)(hc + ((size_t)(t & 1) * 4 + g) * 8192);
    u32x4 r[16];
    u32 exp = (u32)t;
    for (;;) {
#pragma unroll
      for (int i = 0; i < 16; ++i) {
        const void* p = bufr + (size_t)(tid + i * 256) * 16;
        asm volatile("global_load_dwordx4 %0, %1, off sc0 sc1"
                     : "=v"(r[i]) : "v"(p) : "memory");
      }
      asm volatile("s_waitcnt vmcnt(0)" ::: "memory");
      __builtin_amdgcn_sched_barrier(0);
      bool ok = true;
#pragma unroll
      for (int i = 0; i < 16; ++i) ok = ok && (r[i][1] == exp) && (r[i][3] == exp);
      if (ok) break;
      __builtin_amdgcn_s_sleep(1);
    }

    // ---- unpack to LDS: h -> cols [0,512), c -> cols [512,1024) ----
#pragma unroll
    for (int i = 0; i < 16; ++i) {
      int p = tid + i * 256;
      int row = p >> 8, c2 = p & 255;
      u32 hw = (r[i][0] & 0xffffu) | (r[i][2] << 16);
      u32 cw = (r[i][0] >> 16) | (r[i][2] & 0xffff0000u);
      *reinterpret_cast<u32*>(alds + row * 1032 + 2 * c2) = hw;
      *reinterpret_cast<u32*>(alds + row * 1032 + 512 + 2 * c2) = cw;
    }
    __syncthreads();

    // ---- MFMA: 4 independent accumulator chains, B from registers ----
    auto Af = [&](int kk) {
      return *reinterpret_cast<const v8bf*>(alds + col16 * 1032 + kk * 32 + kq * 8);
    };
    v4f ac0, ac1, ac2, ac3;
#pragma unroll
    for (int r4 = 0; r4 < 4; ++r4) { ac0[r4] = seed[r4]; ac1[r4] = 0.f; ac2[r4] = 0.f; ac3[r4] = 0.f; }
    if (w < 3) {
#pragma unroll
      for (int kk = 0; kk < 32; kk += 4) {
        ac0 = __builtin_amdgcn_mfma_f32_16x16x32_bf16(Af(kk + 0), breg[kk + 0], ac0, 0, 0, 0);
        ac1 = __builtin_amdgcn_mfma_f32_16x16x32_bf16(Af(kk + 1), breg[kk + 1], ac1, 0, 0, 0);
        ac2 = __builtin_amdgcn_mfma_f32_16x16x32_bf16(Af(kk + 2), breg[kk + 2], ac2, 0, 0, 0);
        ac3 = __builtin_amdgcn_mfma_f32_16x16x32_bf16(Af(kk + 3), breg[kk + 3], ac3, 0, 0, 0);
      }
    } else {
#pragma unroll
      for (int kk = 0; kk < 16; kk += 4) {
        ac0 = __builtin_amdgcn_mfma_f32_16x16x32_bf16(Af(kk + 0), breg[kk + 0], ac0, 0, 0, 0);
        ac1 = __builtin_amdgcn_mfma_f32_16x16x32_bf16(Af(kk + 1), breg[kk + 1], ac1, 0, 0, 0);
        ac2 = __builtin_amdgcn_mfma_f32_16x16x32_bf16(Af(kk + 2), breg[kk + 2], ac2, 0, 0, 0);
        ac3 = __builtin_amdgcn_mfma_f32_16x16x32_bf16(Af(kk + 3), breg[kk + 3], ac3, 0, 0, 0);
      }
    }
    v4f acc;
#pragma unroll
    for (int r4 = 0; r4 < 4; ++r4) acc[r4] = (ac0[r4] + ac1[r4]) + (ac2[r4] + ac3[r4]);

    // ---- stage gate tiles to LDS f32 ----
#pragma unroll
    for (int r4 = 0; r4 < 4; ++r4) olds[w * 256 + (kq * 4 + r4) * 16 + col16] = acc[r4];
    __syncthreads();

    // ---- elementwise (thread owns (erow, ecol)) ----
    float gi = olds[tid], gf = olds[256 + tid], go = olds[512 + tid], gg = olds[768 + tid];
    float i_s = sigm(gi), f_s = sigm(gf), o_s = sigm(go);
    float cg = tanhf(gg);
    float cy = f_s * c_reg + i_s * cg;
    float hy = o_s * (tanhf(cy) + xi);
    c_reg = cy;

    // ---- fire-and-forget tagged store (data IS the barrier arrive) ----
    u16 hyb = f2b(hy), cyb = f2b(cy);
    u32x2 pkt;
    pkt[0] = (u32)hyb | ((u32)cyb << 16);
    pkt[1] = (u32)(t + 1);
    void* pdst = (char*)(hc + ((size_t)((t + 1) & 1) * 4 + g) * 8192)
                 + (size_t)(erow * 512 + hcol) * 8;
    asm volatile("global_store_dwordx2 %0, %1, off sc0 sc1"
                 :: "v"(pdst), "v"(pkt) : "memory");

    // off critical path: outs / final states
    if (outs_bf16) outs_bf16[(size_t)(t * 64 + bglob) * 512 + hcol] = hyb;
    if (outs_f32)  outs_f32[(size_t)(t * 64 + bglob) * 512 + hcol] = hy;
    if (t == T_STEPS - 1) {
      hn[bglob * 512 + hcol] = hy;
      cn[bglob * 512 + hcol] = cy;
    }
  }
}

// ---------------- launch ----------------

extern "C" void kernel_launch(void* const* d_in, const int* in_sizes, int n_in,
                              void* d_out, int out_size, void* d_ws, size_t ws_size,
                              hipStream_t stream) {
  const float* x   = (const float*)d_in[0];
  const float* Wii = (const float*)d_in[1];
  const float* Wic = (const float*)d_in[2];
  const float* Wih = (const float*)d_in[3];
  const float* bii = (const float*)d_in[4];
  const float* bic = (const float*)d_in[5];
  const float* bih = (const float*)d_in[6];
  const float* Whh = (const float*)d_in[7];
  const float* bhh = (const float*)d_in[8];
  float* out = (float*)d_out;
  char* ws = (char*)d_ws;

  u16* xbf     = (u16*)(ws + OFF_XBF);
  u16* outs1   = (u16*)(ws + OFF_OUTS1);
  u16* xgb     = (u16*)(ws + OFF_XG);
  u16* wiib    = (u16*)(ws + OFF_WII);
  u16* wpack   = (u16*)(ws + OFF_WPACK);
  float* biasf = (float*)(ws + OFF_BIASF);
  u32x2* hc    = (u32x2*)(ws + OFF_HC);

  // prep: bf16 conversions, bias fold, weight packing
  k_cvt <<<2048, 256, 0, stream>>>(x, xbf, 33554432 / 4);
  k_cvt <<<1536, 256, 0, stream>>>(Wii, wiib, 1572864 / 4);
  k_fold<<<12, 256, 0, stream>>>(bii, bic, bih, biasf, 3072);
  k_pack<<<1792, 256, 0, stream>>>(Wih, Wic, Whh, wpack);

  float* hn = out + 33554432;
  float* cn = out + 33554432 + 65536;

  for (int l = 0; l < 2; ++l) {
    k_gemm<<<dim3(512, 12), 256, 0, stream>>>(l ? outs1 : xbf,
                                              wiib + (size_t)l * 786432, xgb);
    // hc overlaps the head of xbf: clear AFTER k_gemm consumed it, BEFORE k_lstm.
    hipMemsetAsync(ws + OFF_HC, 0, 524288, stream);
    k_lstm<<<128, 256, 0, stream>>>(
        xgb, wpack + (size_t)l * 1835008,
        biasf + l * 1536, bhh + l * 512,
        l ? nullptr : x, l ? outs1 : nullptr,
        l ? nullptr : outs1, l ? out : nullptr,
        hn + l * 32768, cn + l * 32768,
        hc);
  }
}

// Round 7
// 7035.751 us; speedup vs baseline: 2.6474x; 1.0086x over previous
//
#include <hip/hip_runtime.h>
#include <cstdint>

typedef unsigned short u16;
typedef unsigned int   u32;
typedef __bf16 v8bf  __attribute__((ext_vector_type(8)));
typedef float  v4f   __attribute__((ext_vector_type(4)));
typedef u32    u32x2 __attribute__((ext_vector_type(2)));
typedef u32    u32x4 __attribute__((ext_vector_type(4)));

#define T_STEPS 1024
#define G3 1536

// ws layout (bytes). Rings overlap the head of xbf (dead after k_gemm; memset
// is issued after k_gemm, before k_lstm).
#define OFF_RING0 0ull          // L0 h/c ring [4 slots][4 grp][16 rows][512] 8B = 1,048,576
#define OFF_RING1 1048576ull    // L1 h/c ring, same shape = 1,048,576
#define OFF_XBF   0ull          // x bf16 [65536,512] 67,108,864 (dead after gemm)
#define OFF_XG    67108864ull   // xg0 bf16 [65536,1536] 201,326,592
#define OFF_WII   268435456ull  // Wii layer0 bf16 [1536,512] 1,572,864
#define OFF_WPACK 270008320ull  // packed recurrent B-frags (2 layers) 7,340,032
#define OFF_WPK2  277348352ull  // packed Wii layer1 B-frags 1,572,864
#define OFF_BIASF 278921216ull  // folded gate bias f32 [2,1536] 12,288

__device__ __forceinline__ u16 f2b(float f) {
  u32 u = __builtin_bit_cast(u32, f);
  u += 0x7fffu + ((u >> 16) & 1u);
  return (u16)(u >> 16);
}
__device__ __forceinline__ float b2f(u16 h) {
  u32 u = ((u32)h) << 16;
  return __builtin_bit_cast(float, u);
}
__device__ __forceinline__ float sigm(float x) { return 1.0f / (1.0f + __expf(-x)); }

// ---------------- prep kernels ----------------

__global__ void k_cvt(const float* __restrict__ s, u16* __restrict__ d, int n4) {
  int i = blockIdx.x * blockDim.x + threadIdx.x;
  int st = gridDim.x * blockDim.x;
  for (; i < n4; i += st) {
    float4 v = reinterpret_cast<const float4*>(s)[i];
    u32 lo = (u32)f2b(v.x) | ((u32)f2b(v.y) << 16);
    u32 hi = (u32)f2b(v.z) | ((u32)f2b(v.w) << 16);
    uint2 pk; pk.x = lo; pk.y = hi;
    reinterpret_cast<uint2*>(d)[i] = pk;
  }
}

__global__ void k_fold(const float* __restrict__ a, const float* __restrict__ b,
                       const float* __restrict__ c, float* __restrict__ o, int n) {
  int i = blockIdx.x * blockDim.x + threadIdx.x;
  if (i < n) o[i] = a[i] + b[i] + c[i];
}

// Recurrent weights -> MFMA B-frag order (both layers). [l][s][112][64][8]:
// c<96: gates tau=c>>5, kk=c&31 (K=1024: k<512 Wih, k>=512 Wic); c>=96: Whh.
__global__ void k_pack(const float* __restrict__ Wih, const float* __restrict__ Wic,
                       const float* __restrict__ Whh, u16* __restrict__ wp) {
  int t = blockIdx.x * blockDim.x + threadIdx.x;
  if (t >= 2 * 32 * 112 * 64) return;
  int lane = t & 63; int rest = t >> 6;
  int c = rest % 112; rest /= 112;
  int s = rest & 31; int l = rest >> 5;
  int col16 = lane & 15, kq = lane >> 4;
  const float* src;
  if (c < 96) {
    int tau = c >> 5, kk = c & 31;
    int col = tau * 512 + s * 16 + col16;
    int k = kk * 32 + kq * 8;
    src = (k < 512) ? (Wih + ((size_t)l * G3 + col) * 512 + k)
                    : (Wic + ((size_t)l * G3 + col) * 512 + (k - 512));
  } else {
    int kk = c - 96;
    int col = s * 16 + col16;
    int k = kk * 32 + kq * 8;
    src = Whh + ((size_t)l * 512 + col) * 512 + k;
  }
  u16 o[8];
#pragma unroll
  for (int i = 0; i < 8; ++i) o[i] = f2b(src[i]);
  uint4 v;
  v.x = (u32)o[0] | ((u32)o[1] << 16);
  v.y = (u32)o[2] | ((u32)o[3] << 16);
  v.z = (u32)o[4] | ((u32)o[5] << 16);
  v.w = (u32)o[6] | ((u32)o[7] << 16);
  reinterpret_cast<uint4*>(wp)[t] = v;
}

// Wii layer-1 -> B-frag order. [s][w][kk(16)][lane(64)][8]; B[k][col]=Wii1[col][k].
__global__ void k_pack2(const float* __restrict__ Wii, u16* __restrict__ wp2) {
  int t = blockIdx.x * blockDim.x + threadIdx.x;
  if (t >= 32 * 3 * 16 * 64) return;
  int lane = t & 63;
  int kk = (t >> 6) & 15;
  int w = (t >> 10) % 3;
  int s = t / 3072;
  int col = w * 512 + s * 16 + (lane & 15);
  int k = kk * 32 + (lane >> 4) * 8;
  const float* src = Wii + ((size_t)G3 + col) * 512 + k;   // layer-1 slice
  u16 o[8];
#pragma unroll
  for (int i = 0; i < 8; ++i) o[i] = f2b(src[i]);
  uint4 v;
  v.x = (u32)o[0] | ((u32)o[1] << 16);
  v.y = (u32)o[2] | ((u32)o[3] << 16);
  v.z = (u32)o[4] | ((u32)o[5] << 16);
  v.w = (u32)o[6] | ((u32)o[7] << 16);
  reinterpret_cast<uint4*>(wp2)[t] = v;
}

// ---------------- xg0 GEMM: C[M,1536] = A[M,512] * Bt[1536,512]^T ----------------

__global__ __launch_bounds__(256) void k_gemm(const u16* __restrict__ A,
                                              const u16* __restrict__ Bt,
                                              u16* __restrict__ C) {
  __shared__ u16 As[128 * 40];
  __shared__ u16 Bs[128 * 40];
  int m0 = blockIdx.x * 128, n0 = blockIdx.y * 128;
  int tid = threadIdx.x, lane = tid & 63, w = tid >> 6, wr = w >> 1, wc = w & 1;
  int rl = lane & 15, kq = lane >> 4;
  v4f acc[4][4] = {};
  for (int k0 = 0; k0 < 512; k0 += 32) {
#pragma unroll
    for (int c = tid; c < 1024; c += 256) {
      int row = (c & 511) >> 2, q = c & 3;
      const u16* src = (c < 512) ? (A + (size_t)(m0 + row) * 512 + k0 + q * 8)
                                 : (Bt + (size_t)(n0 + row) * 512 + k0 + q * 8);
      uint4 v = *reinterpret_cast<const uint4*>(src);
      u16* dst = (c < 512) ? (As + row * 40 + q * 8) : (Bs + row * 40 + q * 8);
      *reinterpret_cast<uint4*>(dst) = v;
    }
    __syncthreads();
    v8bf a[4], b[4];
#pragma unroll
    for (int mi = 0; mi < 4; ++mi)
      a[mi] = *reinterpret_cast<const v8bf*>(As + (wr * 64 + mi * 16 + rl) * 40 + kq * 8);
#pragma unroll
    for (int ni = 0; ni < 4; ++ni)
      b[ni] = *reinterpret_cast<const v8bf*>(Bs + (wc * 64 + ni * 16 + rl) * 40 + kq * 8);
#pragma unroll
    for (int mi = 0; mi < 4; ++mi)
#pragma unroll
      for (int ni = 0; ni < 4; ++ni)
        acc[mi][ni] = __builtin_amdgcn_mfma_f32_16x16x32_bf16(a[mi], b[ni], acc[mi][ni], 0, 0, 0);
    __syncthreads();
  }
#pragma unroll
  for (int mi = 0; mi < 4; ++mi)
#pragma unroll
    for (int ni = 0; ni < 4; ++ni)
#pragma unroll
      for (int r = 0; r < 4; ++r) {
        int row = m0 + wr * 64 + mi * 16 + kq * 4 + r;
        int col = n0 + wc * 64 + ni * 16 + rl;
        C[(size_t)row * G3 + col] = f2b(acc[mi][ni][r]);
      }
}

// ---------------- persistent 2-layer pipelined recurrence ----------------
// 128 blocks (PROVEN co-resident) = 4 groups(16 rows) x 32 slices(16 cols).
// Each block runs BOTH layers; L1 lags one position: at iter t, L0 does pos t,
// L1 does pos t-1 using x1 = h0 tagged t == the bytes this iter's ring0 poll
// already staged. 1025 sequential exchanges total (vs 2048 two-pass).
// Sync: R3-proven tagged 8B packets {h|c<<16, tag} via sc0 sc1, depth-4 rings.

__global__ __launch_bounds__(256, 1) void k_lstm(
    const u16* __restrict__ xg, const u16* __restrict__ wp, const u16* __restrict__ wp2,
    const float* __restrict__ biasf, const float* __restrict__ bhh,
    const float* __restrict__ xin, float* __restrict__ outs,
    float* __restrict__ hn, float* __restrict__ cn,
    char* __restrict__ ring0, char* __restrict__ ring1) {
  extern __shared__ char lds[];
  u16* alds   = (u16*)lds;                 // 16 rows x 2056: [h0|c0|h1|c1]+pad
  float* olds = (float*)(lds + 65792);     // 4 gate tiles [16][16] f32
  u16* w1lds  = (u16*)(lds + 69888);       // Wii1 B-frags: [w(3)][kk(16)][lane][8]
  int tid = threadIdx.x, lane = tid & 63, w = tid >> 6;
  int blk = blockIdx.x, g = blk >> 5, s = blk & 31;

  int erow = tid >> 4, ecol = tid & 15;
  int bglob = g * 16 + erow, hcol = s * 16 + ecol;
  int col16 = lane & 15, kq = lane >> 4;
  float bias0, bias1; int cbase;
  if (w < 3) {
    bias0 = biasf[w * 512 + s * 16 + col16];
    bias1 = biasf[1536 + w * 512 + s * 16 + col16];
    cbase = w * 32;
  } else {
    bias0 = bhh[s * 16 + col16];
    bias1 = bhh[512 + s * 16 + col16];
    cbase = 96;
  }
  int colglob = w * 512 + s * 16 + col16;

  // one-time: recurrent B-frags (both layers) -> registers
  const u16* w0src = wp + (size_t)s * 57344 + (size_t)cbase * 512 + lane * 8;
  const u16* w1src = wp + 1835008 + (size_t)s * 57344 + (size_t)cbase * 512 + lane * 8;
  v8bf breg0[32], breg1[32];
  if (w < 3) {
#pragma unroll
    for (int kk = 0; kk < 32; ++kk) {
      breg0[kk] = *reinterpret_cast<const v8bf*>(w0src + kk * 512);
      breg1[kk] = *reinterpret_cast<const v8bf*>(w1src + kk * 512);
    }
  } else {
#pragma unroll
    for (int kk = 0; kk < 16; ++kk) {
      breg0[kk] = *reinterpret_cast<const v8bf*>(w0src + kk * 512);
      breg1[kk] = *reinterpret_cast<const v8bf*>(w1src + kk * 512);
    }
  }
  // one-time: Wii1 B-frag slice -> LDS (48KB)
  {
    const uint4* src = reinterpret_cast<const uint4*>(wp2) + (size_t)s * 3072;
    for (int i = tid; i < 3072; i += 256)
      reinterpret_cast<uint4*>(w1lds)[i] = src[i];
  }
  float c0 = 0.0f, c1 = 0.0f;
  __syncthreads();

  for (int t = 0; t <= T_STEPS; ++t) {
    bool doL0 = (t < T_STEPS), doL1 = (t > 0);

    // ---- prefetch L0 read-only data (plain cached loads, R3-proven) ----
    float seed0[4]; float xi0 = 0.0f;
    if (doL0) {
      if (w < 3) {
        const u16* xgp = xg + (size_t)(t * 64 + g * 16 + kq * 4) * G3 + colglob;
#pragma unroll
        for (int r4 = 0; r4 < 4; ++r4) seed0[r4] = b2f(xgp[(size_t)r4 * G3]) + bias0;
      } else {
#pragma unroll
        for (int r4 = 0; r4 < 4; ++r4) seed0[r4] = bias0;
      }
      xi0 = xin[(size_t)(t * 64 + bglob) * 512 + hcol];
    }

    // ---- poll ring0 tag t (R3-exact), unpack h0->[0,512) c0->[512,1024) ----
    u32x4 r[16];
    {
      const char* pb = ring0 + ((size_t)(t & 3) * 4 + g) * 65536 + (size_t)tid * 16;
      u32 exp = (u32)t; bool ok = false; u32 it = 0;
      while (!ok) {
#pragma unroll
        for (int i = 0; i < 16; ++i)
          asm volatile("global_load_dwordx4 %0, %1, off sc0 sc1"
                       : "=v"(r[i]) : "v"(pb + (size_t)i * 4096) : "memory");
        asm volatile("s_waitcnt vmcnt(0)" ::: "memory");
        __builtin_amdgcn_sched_barrier(0);
        ok = true;
#pragma unroll
        for (int i = 0; i < 16; ++i) ok = ok && (r[i][1] == exp) && (r[i][3] == exp);
        if (!ok) { if (++it > (1u << 13)) break; __builtin_amdgcn_s_sleep(1); }
      }
      __builtin_amdgcn_sched_barrier(0);
#pragma unroll
      for (int i = 0; i < 16; ++i) {
        u32 hw = (r[i][0] & 0xffffu) | (r[i][2] << 16);
        u32 cw = (r[i][0] >> 16) | (r[i][2] & 0xffff0000u);
        *reinterpret_cast<u32*>(alds + i * 2056 + 2 * tid) = hw;
        *reinterpret_cast<u32*>(alds + i * 2056 + 512 + 2 * tid) = cw;
      }
    }
    // ---- poll ring1 tag t-1, unpack h1->[1024,1536) c1->[1536,2048) ----
    if (doL1) {
      const char* pb = ring1 + ((size_t)((t - 1) & 3) * 4 + g) * 65536 + (size_t)tid * 16;
      u32 exp = (u32)(t - 1); bool ok = false; u32 it = 0;
      while (!ok) {
#pragma unroll
        for (int i = 0; i < 16; ++i)
          asm volatile("global_load_dwordx4 %0, %1, off sc0 sc1"
                       : "=v"(r[i]) : "v"(pb + (size_t)i * 4096) : "memory");
        asm volatile("s_waitcnt vmcnt(0)" ::: "memory");
        __builtin_amdgcn_sched_barrier(0);
        ok = true;
#pragma unroll
        for (int i = 0; i < 16; ++i) ok = ok && (r[i][1] == exp) && (r[i][3] == exp);
        if (!ok) { if (++it > (1u << 13)) break; __builtin_amdgcn_s_sleep(1); }
      }
      __builtin_amdgcn_sched_barrier(0);
#pragma unroll
      for (int i = 0; i < 16; ++i) {
        u32 hw = (r[i][0] & 0xffffu) | (r[i][2] << 16);
        u32 cw = (r[i][0] >> 16) | (r[i][2] & 0xffff0000u);
        *reinterpret_cast<u32*>(alds + i * 2056 + 1024 + 2 * tid) = hw;
        *reinterpret_cast<u32*>(alds + i * 2056 + 1536 + 2 * tid) = cw;
      }
    }
    __syncthreads();   // S1: staging complete

    auto Af = [&](int base, int kk) {
      return *reinterpret_cast<const v8bf*>(alds + col16 * 2056 + base + kk * 32 + kq * 8);
    };

    // =========================== LAYER 0: position t ===========================
    if (doL0) {
      v4f ac0, ac1, ac2, ac3;
#pragma unroll
      for (int r4 = 0; r4 < 4; ++r4) { ac0[r4] = seed0[r4]; ac1[r4] = 0.f; ac2[r4] = 0.f; ac3[r4] = 0.f; }
      if (w < 3) {
#pragma unroll
        for (int kk = 0; kk < 32; kk += 4) {
          ac0 = __builtin_amdgcn_mfma_f32_16x16x32_bf16(Af(0, kk + 0), breg0[kk + 0], ac0, 0, 0, 0);
          ac1 = __builtin_amdgcn_mfma_f32_16x16x32_bf16(Af(0, kk + 1), breg0[kk + 1], ac1, 0, 0, 0);
          ac2 = __builtin_amdgcn_mfma_f32_16x16x32_bf16(Af(0, kk + 2), breg0[kk + 2], ac2, 0, 0, 0);
          ac3 = __builtin_amdgcn_mfma_f32_16x16x32_bf16(Af(0, kk + 3), breg0[kk + 3], ac3, 0, 0, 0);
        }
      } else {
#pragma unroll
        for (int kk = 0; kk < 16; kk += 4) {
          ac0 = __builtin_amdgcn_mfma_f32_16x16x32_bf16(Af(0, kk + 0), breg0[kk + 0], ac0, 0, 0, 0);
          ac1 = __builtin_amdgcn_mfma_f32_16x16x32_bf16(Af(0, kk + 1), breg0[kk + 1], ac1, 0, 0, 0);
          ac2 = __builtin_amdgcn_mfma_f32_16x16x32_bf16(Af(0, kk + 2), breg0[kk + 2], ac2, 0, 0, 0);
          ac3 = __builtin_amdgcn_mfma_f32_16x16x32_bf16(Af(0, kk + 3), breg0[kk + 3], ac3, 0, 0, 0);
        }
      }
      v4f acc;
#pragma unroll
      for (int r4 = 0; r4 < 4; ++r4) acc[r4] = (ac0[r4] + ac1[r4]) + (ac2[r4] + ac3[r4]);
#pragma unroll
      for (int r4 = 0; r4 < 4; ++r4) olds[w * 256 + (kq * 4 + r4) * 16 + col16] = acc[r4];
      __syncthreads(); // S2

      float gi = olds[tid], gf = olds[256 + tid], go = olds[512 + tid], gg = olds[768 + tid];
      float i_s = sigm(gi), f_s = sigm(gf), o_s = sigm(go);
      float cg = tanhf(gg);
      float cy = f_s * c0 + i_s * cg;
      float hy = o_s * (tanhf(cy) + xi0);
      c0 = cy;
      u16 hyb = f2b(hy), cyb = f2b(cy);
      u32x2 pkt;
      pkt[0] = (u32)hyb | ((u32)cyb << 16);
      pkt[1] = (u32)(t + 1);
      void* pd = ring0 + ((size_t)((t + 1) & 3) * 4 + g) * 65536
                 + (size_t)(erow * 512 + hcol) * 8;
      asm volatile("global_store_dwordx2 %0, %1, off sc0 sc1"
                   :: "v"(pd), "v"(pkt) : "memory");
      if (t == T_STEPS - 1) {
        hn[bglob * 512 + hcol] = hy;
        cn[bglob * 512 + hcol] = cy;
      }
    }

    // ========================= LAYER 1: position t-1 =========================
    if (doL1) {
      // x1 residual for own cell: h0(tag t) = L0 output at pos t-1
      float xi1 = b2f(alds[erow * 2056 + hcol]);
      __syncthreads(); // S3: L0 elementwise done with olds
      v4f ac0, ac1, ac2, ac3;
#pragma unroll
      for (int r4 = 0; r4 < 4; ++r4) { ac0[r4] = bias1; ac1[r4] = 0.f; ac2[r4] = 0.f; ac3[r4] = 0.f; }
      if (w < 3) {
#pragma unroll
        for (int kk = 0; kk < 32; kk += 4) {   // h1|c1 recurrent, K=1024
          ac0 = __builtin_amdgcn_mfma_f32_16x16x32_bf16(Af(1024, kk + 0), breg1[kk + 0], ac0, 0, 0, 0);
          ac1 = __builtin_amdgcn_mfma_f32_16x16x32_bf16(Af(1024, kk + 1), breg1[kk + 1], ac1, 0, 0, 0);
          ac2 = __builtin_amdgcn_mfma_f32_16x16x32_bf16(Af(1024, kk + 2), breg1[kk + 2], ac2, 0, 0, 0);
          ac3 = __builtin_amdgcn_mfma_f32_16x16x32_bf16(Af(1024, kk + 3), breg1[kk + 3], ac3, 0, 0, 0);
        }
#pragma unroll
        for (int kk = 0; kk < 16; kk += 4) {   // x1 @ Wii1, K=512, B from LDS
          ac0 = __builtin_amdgcn_mfma_f32_16x16x32_bf16(Af(0, kk + 0),
                  *reinterpret_cast<const v8bf*>(w1lds + ((w * 16 + kk + 0) * 64 + lane) * 8), ac0, 0, 0, 0);
          ac1 = __builtin_amdgcn_mfma_f32_16x16x32_bf16(Af(0, kk + 1),
                  *reinterpret_cast<const v8bf*>(w1lds + ((w * 16 + kk + 1) * 64 + lane) * 8), ac1, 0, 0, 0);
          ac2 = __builtin_amdgcn_mfma_f32_16x16x32_bf16(Af(0, kk + 2),
                  *reinterpret_cast<const v8bf*>(w1lds + ((w * 16 + kk + 2) * 64 + lane) * 8), ac2, 0, 0, 0);
          ac3 = __builtin_amdgcn_mfma_f32_16x16x32_bf16(Af(0, kk + 3),
                  *reinterpret_cast<const v8bf*>(w1lds + ((w * 16 + kk + 3) * 64 + lane) * 8), ac3, 0, 0, 0);
        }
      } else {
#pragma unroll
        for (int kk = 0; kk < 16; kk += 4) {   // cell: h1 only, K=512
          ac0 = __builtin_amdgcn_mfma_f32_16x16x32_bf16(Af(1024, kk + 0), breg1[kk + 0], ac0, 0, 0, 0);
          ac1 = __builtin_amdgcn_mfma_f32_16x16x32_bf16(Af(1024, kk + 1), breg1[kk + 1], ac1, 0, 0, 0);
          ac2 = __builtin_amdgcn_mfma_f32_16x16x32_bf16(Af(1024, kk + 2), breg1[kk + 2], ac2, 0, 0, 0);
          ac3 = __builtin_amdgcn_mfma_f32_16x16x32_bf16(Af(1024, kk + 3), breg1[kk + 3], ac3, 0, 0, 0);
        }
      }
      v4f acc;
#pragma unroll
      for (int r4 = 0; r4 < 4; ++r4) acc[r4] = (ac0[r4] + ac1[r4]) + (ac2[r4] + ac3[r4]);
#pragma unroll
      for (int r4 = 0; r4 < 4; ++r4) olds[w * 256 + (kq * 4 + r4) * 16 + col16] = acc[r4];
      __syncthreads(); // S4

      float gi = olds[tid], gf = olds[256 + tid], go = olds[512 + tid], gg = olds[768 + tid];
      float i_s = sigm(gi), f_s = sigm(gf), o_s = sigm(go);
      float cg = tanhf(gg);
      float cy = f_s * c1 + i_s * cg;
      float hy = o_s * (tanhf(cy) + xi1);
      c1 = cy;
      u16 hyb = f2b(hy), cyb = f2b(cy);
      u32x2 pkt;
      pkt[0] = (u32)hyb | ((u32)cyb << 16);
      pkt[1] = (u32)t;
      void* pd = ring1 + ((size_t)(t & 3) * 4 + g) * 65536
                 + (size_t)(erow * 512 + hcol) * 8;
      asm volatile("global_store_dwordx2 %0, %1, off sc0 sc1"
                   :: "v"(pd), "v"(pkt) : "memory");
      outs[(size_t)((t - 1) * 64 + bglob) * 512 + hcol] = hy;
      if (t == T_STEPS) {
        hn[32768 + bglob * 512 + hcol] = hy;
        cn[32768 + bglob * 512 + hcol] = cy;
      }
    }
    __syncthreads(); // S5: all alds reads done before next iter's unpack writes
  }
}

// ---------------- launch ----------------

extern "C" void kernel_launch(void* const* d_in, const int* in_sizes, int n_in,
                              void* d_out, int out_size, void* d_ws, size_t ws_size,
                              hipStream_t stream) {
  const float* x   = (const float*)d_in[0];
  const float* Wii = (const float*)d_in[1];
  const float* Wic = (const float*)d_in[2];
  const float* Wih = (const float*)d_in[3];
  const float* bii = (const float*)d_in[4];
  const float* bic = (const float*)d_in[5];
  const float* bih = (const float*)d_in[6];
  const float* Whh = (const float*)d_in[7];
  const float* bhh = (const float*)d_in[8];
  float* out = (float*)d_out;
  char* ws = (char*)d_ws;

  u16* xbf     = (u16*)(ws + OFF_XBF);
  u16* xgb     = (u16*)(ws + OFF_XG);
  u16* wiib    = (u16*)(ws + OFF_WII);
  u16* wpack   = (u16*)(ws + OFF_WPACK);
  u16* wpk2    = (u16*)(ws + OFF_WPK2);
  float* biasf = (float*)(ws + OFF_BIASF);

  hipFuncSetAttribute(reinterpret_cast<const void*>(k_lstm),
                      hipFuncAttributeMaxDynamicSharedMemorySize, 119040);

  // prep
  k_cvt <<<2048, 256, 0, stream>>>(x, xbf, 8388608);
  k_cvt <<<768, 256, 0, stream>>>(Wii, wiib, 196608);          // layer-0 Wii only
  k_fold<<<12, 256, 0, stream>>>(bii, bic, bih, biasf, 3072);
  k_pack<<<1792, 256, 0, stream>>>(Wih, Wic, Whh, wpack);
  k_pack2<<<384, 256, 0, stream>>>(Wii, wpk2);
  k_gemm<<<dim3(512, 12), 256, 0, stream>>>(xbf, wiib, xgb);   // xg0 only

  // rings overlap head of xbf: clear AFTER k_gemm consumed it.
  hipMemsetAsync(ws + OFF_RING0, 0, 2097152, stream);

  float* hn = out + 33554432;
  float* cn = out + 33554432 + 65536;
  k_lstm<<<128, 256, 119040, stream>>>(
      xgb, wpack, wpk2, biasf, bhh, x, out, hn, cn,
      ws + OFF_RING0, ws + OFF_RING1);
}

// Round 8
// 5537.888 us; speedup vs baseline: 3.3635x; 1.2705x over previous
//
#include <hip/hip_runtime.h>
#include <cstdint>

typedef unsigned short u16;
typedef unsigned int   u32;
typedef __bf16 v8bf  __attribute__((ext_vector_type(8)));
typedef float  v4f   __attribute__((ext_vector_type(4)));
typedef u32    u32x2 __attribute__((ext_vector_type(2)));
typedef u32    u32x4 __attribute__((ext_vector_type(4)));

#define T_STEPS 1024
#define G3 1536

// ws layout (bytes). Rings overlap the head of xbf (dead after k_gemm; memset
// is issued after k_gemm, before k_lstm).
#define OFF_RING0 0ull          // L0 h/c ring [4 slots][4 grp][16 rows][512] 8B = 1,048,576
#define OFF_RING1 1048576ull    // L1 h/c ring, same shape = 1,048,576
#define OFF_XBF   0ull          // x bf16 [65536,512] 67,108,864 (dead after gemm)
#define OFF_XG    67108864ull   // xg0 bf16 [65536,1536] 201,326,592
#define OFF_WII   268435456ull  // Wii layer0 bf16 [1536,512] 1,572,864
#define OFF_WPACK 270008320ull  // packed recurrent B-frags (2 layers) 7,340,032
#define OFF_WPK2  277348352ull  // packed Wii layer1 B-frags 1,572,864
#define OFF_BIASF 278921216ull  // folded gate bias f32 [2,1536] 12,288

__device__ __forceinline__ u16 f2b(float f) {
  u32 u = __builtin_bit_cast(u32, f);
  u += 0x7fffu + ((u >> 16) & 1u);
  return (u16)(u >> 16);
}
__device__ __forceinline__ float b2f(u16 h) {
  u32 u = ((u32)h) << 16;
  return __builtin_bit_cast(float, u);
}
__device__ __forceinline__ float sigm(float x) { return 1.0f / (1.0f + __expf(-x)); }

// ---------------- prep kernels ----------------

__global__ void k_cvt(const float* __restrict__ s, u16* __restrict__ d, int n4) {
  int i = blockIdx.x * blockDim.x + threadIdx.x;
  int st = gridDim.x * blockDim.x;
  for (; i < n4; i += st) {
    float4 v = reinterpret_cast<const float4*>(s)[i];
    u32 lo = (u32)f2b(v.x) | ((u32)f2b(v.y) << 16);
    u32 hi = (u32)f2b(v.z) | ((u32)f2b(v.w) << 16);
    uint2 pk; pk.x = lo; pk.y = hi;
    reinterpret_cast<uint2*>(d)[i] = pk;
  }
}

__global__ void k_fold(const float* __restrict__ a, const float* __restrict__ b,
                       const float* __restrict__ c, float* __restrict__ o, int n) {
  int i = blockIdx.x * blockDim.x + threadIdx.x;
  if (i < n) o[i] = a[i] + b[i] + c[i];
}

// Recurrent weights -> MFMA B-frag order (both layers). [l][s][112][64][8]:
// c<96: gates tau=c>>5, kk=c&31 (K=1024: k<512 Wih, k>=512 Wic); c>=96: Whh.
__global__ void k_pack(const float* __restrict__ Wih, const float* __restrict__ Wic,
                       const float* __restrict__ Whh, u16* __restrict__ wp) {
  int t = blockIdx.x * blockDim.x + threadIdx.x;
  if (t >= 2 * 32 * 112 * 64) return;
  int lane = t & 63; int rest = t >> 6;
  int c = rest % 112; rest /= 112;
  int s = rest & 31; int l = rest >> 5;
  int col16 = lane & 15, kq = lane >> 4;
  const float* src;
  if (c < 96) {
    int tau = c >> 5, kk = c & 31;
    int col = tau * 512 + s * 16 + col16;
    int k = kk * 32 + kq * 8;
    src = (k < 512) ? (Wih + ((size_t)l * G3 + col) * 512 + k)
                    : (Wic + ((size_t)l * G3 + col) * 512 + (k - 512));
  } else {
    int kk = c - 96;
    int col = s * 16 + col16;
    int k = kk * 32 + kq * 8;
    src = Whh + ((size_t)l * 512 + col) * 512 + k;
  }
  u16 o[8];
#pragma unroll
  for (int i = 0; i < 8; ++i) o[i] = f2b(src[i]);
  uint4 v;
  v.x = (u32)o[0] | ((u32)o[1] << 16);
  v.y = (u32)o[2] | ((u32)o[3] << 16);
  v.z = (u32)o[4] | ((u32)o[5] << 16);
  v.w = (u32)o[6] | ((u32)o[7] << 16);
  reinterpret_cast<uint4*>(wp)[t] = v;
}

// Wii layer-1 -> B-frag order. [s][w2(3)][kk(16)][lane(64)][8]; B[k][col]=Wii1[col][k].
__global__ void k_pack2(const float* __restrict__ Wii, u16* __restrict__ wp2) {
  int t = blockIdx.x * blockDim.x + threadIdx.x;
  if (t >= 32 * 3 * 16 * 64) return;
  int lane = t & 63;
  int kk = (t >> 6) & 15;
  int w = (t >> 10) % 3;
  int s = t / 3072;
  int col = w * 512 + s * 16 + (lane & 15);
  int k = kk * 32 + (lane >> 4) * 8;
  const float* src = Wii + ((size_t)G3 + col) * 512 + k;   // layer-1 slice
  u16 o[8];
#pragma unroll
  for (int i = 0; i < 8; ++i) o[i] = f2b(src[i]);
  uint4 v;
  v.x = (u32)o[0] | ((u32)o[1] << 16);
  v.y = (u32)o[2] | ((u32)o[3] << 16);
  v.z = (u32)o[4] | ((u32)o[5] << 16);
  v.w = (u32)o[6] | ((u32)o[7] << 16);
  reinterpret_cast<uint4*>(wp2)[t] = v;
}

// ---------------- xg0 GEMM: C[M,1536] = A[M,512] * Bt[1536,512]^T ----------------

__global__ __launch_bounds__(256) void k_gemm(const u16* __restrict__ A,
                                              const u16* __restrict__ Bt,
                                              u16* __restrict__ C) {
  __shared__ u16 As[128 * 40];
  __shared__ u16 Bs[128 * 40];
  int m0 = blockIdx.x * 128, n0 = blockIdx.y * 128;
  int tid = threadIdx.x, lane = tid & 63, w = tid >> 6, wr = w >> 1, wc = w & 1;
  int rl = lane & 15, kq = lane >> 4;
  v4f acc[4][4] = {};
  for (int k0 = 0; k0 < 512; k0 += 32) {
#pragma unroll
    for (int c = tid; c < 1024; c += 256) {
      int row = (c & 511) >> 2, q = c & 3;
      const u16* src = (c < 512) ? (A + (size_t)(m0 + row) * 512 + k0 + q * 8)
                                 : (Bt + (size_t)(n0 + row) * 512 + k0 + q * 8);
      uint4 v = *reinterpret_cast<const uint4*>(src);
      u16* dst = (c < 512) ? (As + row * 40 + q * 8) : (Bs + row * 40 + q * 8);
      *reinterpret_cast<uint4*>(dst) = v;
    }
    __syncthreads();
    v8bf a[4], b[4];
#pragma unroll
    for (int mi = 0; mi < 4; ++mi)
      a[mi] = *reinterpret_cast<const v8bf*>(As + (wr * 64 + mi * 16 + rl) * 40 + kq * 8);
#pragma unroll
    for (int ni = 0; ni < 4; ++ni)
      b[ni] = *reinterpret_cast<const v8bf*>(Bs + (wc * 64 + ni * 16 + rl) * 40 + kq * 8);
#pragma unroll
    for (int mi = 0; mi < 4; ++mi)
#pragma unroll
      for (int ni = 0; ni < 4; ++ni)
        acc[mi][ni] = __builtin_amdgcn_mfma_f32_16x16x32_bf16(a[mi], b[ni], acc[mi][ni], 0, 0, 0);
    __syncthreads();
  }
#pragma unroll
  for (int mi = 0; mi < 4; ++mi)
#pragma unroll
    for (int ni = 0; ni < 4; ++ni)
#pragma unroll
      for (int r = 0; r < 4; ++r) {
        int row = m0 + wr * 64 + mi * 16 + kq * 4 + r;
        int col = n0 + wc * 64 + ni * 16 + rl;
        C[(size_t)row * G3 + col] = f2b(acc[mi][ni][r]);
      }
}

// ---------------- persistent 2-layer pipelined recurrence ----------------
// 128 blocks x 512 threads (8 waves). Same-block layer pipelining (R7-proven
// protocol): at iter t, L0 does pos t, L1 does pos t-1 with x1 = h0 tag t (the
// ring0 bytes this iter already staged). Per-gate compute split across 2 waves
// (K halves) so per-thread weight fragments halve -> no VGPR spills; partial
// C-tiles summed via olds at the elementwise read. Ring1's loads are issued
// BEFORE L0's compute and tag-checked after it (latency hidden under L0).
// Sync: R3-proven tagged 8B packets {h|c<<16, tag} via sc0 sc1, depth-4 rings.

__global__ __launch_bounds__(512, 1) void k_lstm(
    const u16* __restrict__ xg, const u16* __restrict__ wp, const u16* __restrict__ wp2,
    const float* __restrict__ biasf, const float* __restrict__ bhh,
    const float* __restrict__ xin, float* __restrict__ outs,
    float* __restrict__ hn, float* __restrict__ cn,
    char* __restrict__ ring0, char* __restrict__ ring1) {
  extern __shared__ char lds[];
  u16* alds   = (u16*)lds;                 // 16 rows x 2056 u16: [h0|c0|h1|c1]+pad
  float* olds = (float*)(lds + 65792);     // 8 wave-tiles [16][16] f32 (gate halves)
  u16* w1lds  = (u16*)(lds + 73984);       // Wii1 B-frags: [w2(3)][kk(16)][lane][8]
  int tid = threadIdx.x, lane = tid & 63, w = tid >> 6;
  int w2 = w >> 1, half = w & 1;           // gate index / K-half
  int blk = blockIdx.x, g = blk >> 5, s = blk & 31;

  int erow = (tid >> 4) & 15, ecol = tid & 15;   // elementwise ownership (tid<256)
  int bglob = g * 16 + erow, hcol = s * 16 + ecol;
  int col16 = lane & 15, kq = lane >> 4;
  bool isGate = (w2 < 3);
  float bias0 = 0.0f, bias1 = 0.0f;
  int cbase, nch;
  if (isGate) {
    cbase = w2 * 32 + half * 16; nch = 16;
    if (half == 0) {
      bias0 = biasf[w2 * 512 + s * 16 + col16];
      bias1 = biasf[1536 + w2 * 512 + s * 16 + col16];
    }
  } else {
    cbase = 96 + half * 8; nch = 8;
    if (half == 0) {
      bias0 = bhh[s * 16 + col16];
      bias1 = bhh[512 + s * 16 + col16];
    }
  }
  int colglob = w2 * 512 + s * 16 + col16;

  // one-time: recurrent B-frags (both layers, this wave's K-half) -> registers
  const u16* w0src = wp + (size_t)s * 57344 + (size_t)cbase * 512 + lane * 8;
  const u16* w1src = wp + 1835008 + (size_t)s * 57344 + (size_t)cbase * 512 + lane * 8;
  v8bf breg0[16], breg1[16];
  if (isGate) {
#pragma unroll
    for (int kk = 0; kk < 16; ++kk) {
      breg0[kk] = *reinterpret_cast<const v8bf*>(w0src + kk * 512);
      breg1[kk] = *reinterpret_cast<const v8bf*>(w1src + kk * 512);
    }
  } else {
#pragma unroll
    for (int kk = 0; kk < 8; ++kk) {
      breg0[kk] = *reinterpret_cast<const v8bf*>(w0src + kk * 512);
      breg1[kk] = *reinterpret_cast<const v8bf*>(w1src + kk * 512);
    }
  }
  // one-time: Wii1 B-frag slice -> LDS (48KB)
  {
    const uint4* src = reinterpret_cast<const uint4*>(wp2) + (size_t)s * 3072;
    for (int i = tid; i < 3072; i += 512)
      reinterpret_cast<uint4*>(w1lds)[i] = src[i];
  }
  float c0 = 0.0f, c1 = 0.0f;
  __syncthreads();

  auto Af = [&](int base, int kg) {
    return *reinterpret_cast<const v8bf*>(alds + col16 * 2056 + base + kg * 32 + kq * 8);
  };

  for (int t = 0; t <= T_STEPS; ++t) {
    bool doL0 = (t < T_STEPS), doL1 = (t > 0);

    // ---- prefetch L0 read-only data (plain cached loads; drained by poll0) ----
    float seed0[4] = {0.f, 0.f, 0.f, 0.f};
    float xi0 = 0.0f;
    if (doL0) {
      if (isGate) {
        if (half == 0) {
          const u16* xgp = xg + (size_t)(t * 64 + g * 16 + kq * 4) * G3 + colglob;
#pragma unroll
          for (int r4 = 0; r4 < 4; ++r4) seed0[r4] = b2f(xgp[(size_t)r4 * G3]) + bias0;
        }
      } else if (half == 0) {
#pragma unroll
        for (int r4 = 0; r4 < 4; ++r4) seed0[r4] = bias0;
      }
      if (tid < 256) xi0 = xin[(size_t)(t * 64 + bglob) * 512 + hcol];
    }

    // ---- poll ring0 tag t (needed by L0 AND by L1's x1 term) ----
    u32x4 r[8];
    {
      const char* pb = ring0 + ((size_t)(t & 3) * 4 + g) * 65536 + (size_t)tid * 16;
      u32 exp = (u32)t; bool ok = false; u32 it = 0;
      while (!ok) {
#pragma unroll
        for (int i = 0; i < 8; ++i)
          asm volatile("global_load_dwordx4 %0, %1, off sc0 sc1"
                       : "=v"(r[i]) : "v"(pb + (size_t)i * 8192) : "memory");
        asm volatile("s_waitcnt vmcnt(0)" ::: "memory");
        __builtin_amdgcn_sched_barrier(0);
        ok = true;
#pragma unroll
        for (int i = 0; i < 8; ++i) ok = ok && (r[i][1] == exp) && (r[i][3] == exp);
        if (!ok) { if (++it > (1u << 11)) break; __builtin_amdgcn_s_sleep(1); }
      }
      __builtin_amdgcn_sched_barrier(0);
#pragma unroll
      for (int i = 0; i < 8; ++i) {
        int p = tid + i * 512;
        int row = p >> 8, c2 = p & 255;
        u32 hw = (r[i][0] & 0xffffu) | (r[i][2] << 16);
        u32 cw = (r[i][0] >> 16) | (r[i][2] & 0xffff0000u);
        *reinterpret_cast<u32*>(alds + row * 2056 + 2 * c2) = hw;
        *reinterpret_cast<u32*>(alds + row * 2056 + 512 + 2 * c2) = cw;
      }
    }

    // ---- issue ring1 loads EARLY (checked after L0; latency hidden) ----
    u32x4 r2[8];
    if (doL1) {
      const char* pb = ring1 + ((size_t)((t - 1) & 3) * 4 + g) * 65536 + (size_t)tid * 16;
#pragma unroll
      for (int i = 0; i < 8; ++i)
        asm volatile("global_load_dwordx4 %0, %1, off sc0 sc1"
                     : "=v"(r2[i]) : "v"(pb + (size_t)i * 8192) : "memory");
    }
    __syncthreads();   // S1: ring0 staged

    // =========================== LAYER 0: position t ===========================
    if (doL0) {
      v4f ac0, ac1, ac2, ac3;
#pragma unroll
      for (int r4 = 0; r4 < 4; ++r4) { ac0[r4] = seed0[r4]; ac1[r4] = 0.f; ac2[r4] = 0.f; ac3[r4] = 0.f; }
      if (isGate) {
#pragma unroll
        for (int kk = 0; kk < 16; kk += 4) {
          int kg = half * 16 + kk;
          ac0 = __builtin_amdgcn_mfma_f32_16x16x32_bf16(Af(0, kg + 0), breg0[kk + 0], ac0, 0, 0, 0);
          ac1 = __builtin_amdgcn_mfma_f32_16x16x32_bf16(Af(0, kg + 1), breg0[kk + 1], ac1, 0, 0, 0);
          ac2 = __builtin_amdgcn_mfma_f32_16x16x32_bf16(Af(0, kg + 2), breg0[kk + 2], ac2, 0, 0, 0);
          ac3 = __builtin_amdgcn_mfma_f32_16x16x32_bf16(Af(0, kg + 3), breg0[kk + 3], ac3, 0, 0, 0);
        }
      } else {
#pragma unroll
        for (int kk = 0; kk < 8; kk += 4) {
          int kg = half * 8 + kk;
          ac0 = __builtin_amdgcn_mfma_f32_16x16x32_bf16(Af(0, kg + 0), breg0[kk + 0], ac0, 0, 0, 0);
          ac1 = __builtin_amdgcn_mfma_f32_16x16x32_bf16(Af(0, kg + 1), breg0[kk + 1], ac1, 0, 0, 0);
          ac2 = __builtin_amdgcn_mfma_f32_16x16x32_bf16(Af(0, kg + 2), breg0[kk + 2], ac2, 0, 0, 0);
          ac3 = __builtin_amdgcn_mfma_f32_16x16x32_bf16(Af(0, kg + 3), breg0[kk + 3], ac3, 0, 0, 0);
        }
      }
      v4f acc;
#pragma unroll
      for (int r4 = 0; r4 < 4; ++r4) acc[r4] = (ac0[r4] + ac1[r4]) + (ac2[r4] + ac3[r4]);
#pragma unroll
      for (int r4 = 0; r4 < 4; ++r4) olds[w * 256 + (kq * 4 + r4) * 16 + col16] = acc[r4];
      __syncthreads(); // S2

      if (tid < 256) {
        float gi = olds[tid] + olds[256 + tid];
        float gf = olds[512 + tid] + olds[768 + tid];
        float go = olds[1024 + tid] + olds[1280 + tid];
        float gg = olds[1536 + tid] + olds[1792 + tid];
        float i_s = sigm(gi), f_s = sigm(gf), o_s = sigm(go);
        float cg = tanhf(gg);
        float cy = f_s * c0 + i_s * cg;
        float hy = o_s * (tanhf(cy) + xi0);
        c0 = cy;
        u16 hyb = f2b(hy), cyb = f2b(cy);
        u32x2 pkt;
        pkt[0] = (u32)hyb | ((u32)cyb << 16);
        pkt[1] = (u32)(t + 1);
        void* pd = ring0 + ((size_t)((t + 1) & 3) * 4 + g) * 65536
                   + (size_t)(erow * 512 + hcol) * 8;
        asm volatile("global_store_dwordx2 %0, %1, off sc0 sc1"
                     :: "v"(pd), "v"(pkt) : "memory");
        if (t == T_STEPS - 1) {
          hn[bglob * 512 + hcol] = hy;
          cn[bglob * 512 + hcol] = cy;
        }
      }
    }

    // ========================= LAYER 1: position t-1 =========================
    if (doL1) {
      float xi1 = (tid < 256) ? b2f(alds[erow * 2056 + hcol]) : 0.0f;  // h0 tag t

      // deferred ring1 check (loads issued pre-L0; drain + verify + retry)
      {
        const char* pb = ring1 + ((size_t)((t - 1) & 3) * 4 + g) * 65536 + (size_t)tid * 16;
        u32 exp = (u32)(t - 1); u32 it = 0;
        for (;;) {
          asm volatile("s_waitcnt vmcnt(0)" ::: "memory");
          __builtin_amdgcn_sched_barrier(0);
          bool ok = true;
#pragma unroll
          for (int i = 0; i < 8; ++i) ok = ok && (r2[i][1] == exp) && (r2[i][3] == exp);
          if (ok) break;
          if (++it > (1u << 11)) break;
          __builtin_amdgcn_s_sleep(1);
#pragma unroll
          for (int i = 0; i < 8; ++i)
            asm volatile("global_load_dwordx4 %0, %1, off sc0 sc1"
                         : "=v"(r2[i]) : "v"(pb + (size_t)i * 8192) : "memory");
        }
        __builtin_amdgcn_sched_barrier(0);
#pragma unroll
        for (int i = 0; i < 8; ++i) {
          int p = tid + i * 512;
          int row = p >> 8, c2 = p & 255;
          u32 hw = (r2[i][0] & 0xffffu) | (r2[i][2] << 16);
          u32 cw = (r2[i][0] >> 16) | (r2[i][2] & 0xffff0000u);
          *reinterpret_cast<u32*>(alds + row * 2056 + 1024 + 2 * c2) = hw;
          *reinterpret_cast<u32*>(alds + row * 2056 + 1536 + 2 * c2) = cw;
        }
      }
      __syncthreads(); // S3: ring1 staged; L0 done with olds

      v4f ac0, ac1, ac2, ac3;
#pragma unroll
      for (int r4 = 0; r4 < 4; ++r4) { ac0[r4] = bias1; ac1[r4] = 0.f; ac2[r4] = 0.f; ac3[r4] = 0.f; }
      if (isGate) {
#pragma unroll
        for (int kk = 0; kk < 16; kk += 4) {   // h1|c1 recurrent, this K-half
          int kg = half * 16 + kk;
          ac0 = __builtin_amdgcn_mfma_f32_16x16x32_bf16(Af(1024, kg + 0), breg1[kk + 0], ac0, 0, 0, 0);
          ac1 = __builtin_amdgcn_mfma_f32_16x16x32_bf16(Af(1024, kg + 1), breg1[kk + 1], ac1, 0, 0, 0);
          ac2 = __builtin_amdgcn_mfma_f32_16x16x32_bf16(Af(1024, kg + 2), breg1[kk + 2], ac2, 0, 0, 0);
          ac3 = __builtin_amdgcn_mfma_f32_16x16x32_bf16(Af(1024, kg + 3), breg1[kk + 3], ac3, 0, 0, 0);
        }
#pragma unroll
        for (int kx = 0; kx < 8; kx += 4) {    // x1 @ Wii1, this K-half (8 of 16)
          int kg = half * 8 + kx;
          ac0 = __builtin_amdgcn_mfma_f32_16x16x32_bf16(Af(0, kg + 0),
                  *reinterpret_cast<const v8bf*>(w1lds + ((w2 * 16 + kg + 0) * 64 + lane) * 8), ac0, 0, 0, 0);
          ac1 = __builtin_amdgcn_mfma_f32_16x16x32_bf16(Af(0, kg + 1),
                  *reinterpret_cast<const v8bf*>(w1lds + ((w2 * 16 + kg + 1) * 64 + lane) * 8), ac1, 0, 0, 0);
          ac2 = __builtin_amdgcn_mfma_f32_16x16x32_bf16(Af(0, kg + 2),
                  *reinterpret_cast<const v8bf*>(w1lds + ((w2 * 16 + kg + 2) * 64 + lane) * 8), ac2, 0, 0, 0);
          ac3 = __builtin_amdgcn_mfma_f32_16x16x32_bf16(Af(0, kg + 3),
                  *reinterpret_cast<const v8bf*>(w1lds + ((w2 * 16 + kg + 3) * 64 + lane) * 8), ac3, 0, 0, 0);
        }
      } else {
#pragma unroll
        for (int kk = 0; kk < 8; kk += 4) {    // cell: h1 only, this K-half
          int kg = half * 8 + kk;
          ac0 = __builtin_amdgcn_mfma_f32_16x16x32_bf16(Af(1024, kg + 0), breg1[kk + 0], ac0, 0, 0, 0);
          ac1 = __builtin_amdgcn_mfma_f32_16x16x32_bf16(Af(1024, kg + 1), breg1[kk + 1], ac1, 0, 0, 0);
          ac2 = __builtin_amdgcn_mfma_f32_16x16x32_bf16(Af(1024, kg + 2), breg1[kk + 2], ac2, 0, 0, 0);
          ac3 = __builtin_amdgcn_mfma_f32_16x16x32_bf16(Af(1024, kg + 3), breg1[kk + 3], ac3, 0, 0, 0);
        }
      }
      v4f acc;
#pragma unroll
      for (int r4 = 0; r4 < 4; ++r4) acc[r4] = (ac0[r4] + ac1[r4]) + (ac2[r4] + ac3[r4]);
#pragma unroll
      for (int r4 = 0; r4 < 4; ++r4) olds[w * 256 + (kq * 4 + r4) * 16 + col16] = acc[r4];
      __syncthreads(); // S4

      if (tid < 256) {
        float gi = olds[tid] + olds[256 + tid];
        float gf = olds[512 + tid] + olds[768 + tid];
        float go = olds[1024 + tid] + olds[1280 + tid];
        float gg = olds[1536 + tid] + olds[1792 + tid];
        float i_s = sigm(gi), f_s = sigm(gf), o_s = sigm(go);
        float cg = tanhf(gg);
        float cy = f_s * c1 + i_s * cg;
        float hy = o_s * (tanhf(cy) + xi1);
        c1 = cy;
        u16 hyb = f2b(hy), cyb = f2b(cy);
        u32x2 pkt;
        pkt[0] = (u32)hyb | ((u32)cyb << 16);
        pkt[1] = (u32)t;
        void* pd = ring1 + ((size_t)(t & 3) * 4 + g) * 65536
                   + (size_t)(erow * 512 + hcol) * 8;
        asm volatile("global_store_dwordx2 %0, %1, off sc0 sc1"
                     :: "v"(pd), "v"(pkt) : "memory");
        outs[(size_t)((t - 1) * 64 + bglob) * 512 + hcol] = hy;
        if (t == T_STEPS) {
          hn[32768 + bglob * 512 + hcol] = hy;
          cn[32768 + bglob * 512 + hcol] = cy;
        }
      }
    }
    __syncthreads(); // S5: all alds reads done before next iter's unpack writes
  }
}

// ---------------- launch ----------------

extern "C" void kernel_launch(void* const* d_in, const int* in_sizes, int n_in,
                              void* d_out, int out_size, void* d_ws, size_t ws_size,
                              hipStream_t stream) {
  const float* x   = (const float*)d_in[0];
  const float* Wii = (const float*)d_in[1];
  const float* Wic = (const float*)d_in[2];
  const float* Wih = (const float*)d_in[3];
  const float* bii = (const float*)d_in[4];
  const float* bic = (const float*)d_in[5];
  const float* bih = (const float*)d_in[6];
  const float* Whh = (const float*)d_in[7];
  const float* bhh = (const float*)d_in[8];
  float* out = (float*)d_out;
  char* ws = (char*)d_ws;

  u16* xbf     = (u16*)(ws + OFF_XBF);
  u16* xgb     = (u16*)(ws + OFF_XG);
  u16* wiib    = (u16*)(ws + OFF_WII);
  u16* wpack   = (u16*)(ws + OFF_WPACK);
  u16* wpk2    = (u16*)(ws + OFF_WPK2);
  float* biasf = (float*)(ws + OFF_BIASF);

  hipFuncSetAttribute(reinterpret_cast<const void*>(k_lstm),
                      hipFuncAttributeMaxDynamicSharedMemorySize, 123136);

  // prep
  k_cvt <<<2048, 256, 0, stream>>>(x, xbf, 8388608);
  k_cvt <<<768, 256, 0, stream>>>(Wii, wiib, 196608);          // layer-0 Wii only
  k_fold<<<12, 256, 0, stream>>>(bii, bic, bih, biasf, 3072);
  k_pack<<<1792, 256, 0, stream>>>(Wih, Wic, Whh, wpack);
  k_pack2<<<384, 256, 0, stream>>>(Wii, wpk2);
  k_gemm<<<dim3(512, 12), 256, 0, stream>>>(xbf, wiib, xgb);   // xg0 only

  // rings overlap head of xbf: clear AFTER k_gemm consumed it.
  hipMemsetAsync(ws + OFF_RING0, 0, 2097152, stream);

  float* hn = out + 33554432;
  float* cn = out + 33554432 + 65536;
  k_lstm<<<128, 512, 123136, stream>>>(
      xgb, wpack, wpk2, biasf, bhh, x, out, hn, cn,
      ws + OFF_RING0, ws + OFF_RING1);
}